// Round 16
// baseline (664.783 us; speedup 1.0000x reference)
//
#include <hip/hip_runtime.h>
#include <math.h>

#define NN 100000   // nodes
#define NE 300000   // edges
#define NG 2000     // graphs
#define HID 256
#define CIN 59
#define KPAD 64     // CIN padded to MFMA K
#define EPSV 1e-5f

#define SCAN_CHUNK 1024
#define NCHUNK ((NN + SCAN_CHUNK - 1) / SCAN_CHUNK)   // 98

typedef __attribute__((ext_vector_type(8))) short bf16x8;   // 8 bf16 (4 VGPRs)
typedef __attribute__((ext_vector_type(4))) float f32x4;

// Activations (and pooled) live in a row-swizzled global layout: element
// (r,k) at ushort index r*HID + (k ^ ((r&7)<<3)).  Linear global->LDS copy
// then yields conflict-free ds_read_b128 in the GEMM.
__device__ __forceinline__ int swzk(int row, int k) { return k ^ ((row & 7) << 3); }

// ---------- f32 -> (bf16 hi, bf16 lo) split, round-to-nearest ----------
__device__ inline void splitbf(float x, ushort& hi, ushort& lo) {
  union { float f; unsigned u; } a; a.f = x;
  unsigned r = a.u + 0x7FFFu + ((a.u >> 16) & 1u);
  hi = (ushort)(r >> 16);
  union { unsigned u; float f; } h; h.u = (unsigned)hi << 16;
  union { float f; unsigned u; } d; d.f = x - h.f;
  unsigned r2 = d.u + 0x7FFFu + ((d.u >> 16) & 1u);
  lo = (ushort)(r2 >> 16);
}
__device__ inline float joinbf(ushort hi, ushort lo) {
  union { unsigned u; float f; } a, b;
  a.u = (unsigned)hi << 16; b.u = (unsigned)lo << 16;
  return a.f + b.f;
}

__device__ __forceinline__ void gload16(const ushort* g, ushort* l) {
  __builtin_amdgcn_global_load_lds(
      (const __attribute__((address_space(1))) unsigned int*)g,
      (__attribute__((address_space(3))) unsigned int*)l, 16, 0, 0);
}

// ---------------- degree / CSR build ----------------

__global__ __launch_bounds__(256) void k_deg(const int* __restrict__ ei, int* __restrict__ deg) {
  int e = blockIdx.x * 256 + threadIdx.x;
  if (e < NE) atomicAdd(&deg[ei[NE + e]], 1);   // dst = ei[1][e]
}

__global__ __launch_bounds__(256) void k_scanA(const int* __restrict__ deg, int* __restrict__ part) {
  __shared__ int sm[256];
  int b = blockIdx.x, t = threadIdx.x;
  int base = b * SCAN_CHUNK + t * 4;
  int s = 0;
#pragma unroll
  for (int j = 0; j < 4; ++j) { int idx = base + j; if (idx < NN) s += deg[idx]; }
  sm[t] = s; __syncthreads();
  for (int off = 128; off > 0; off >>= 1) {
    if (t < off) sm[t] += sm[t + off];
    __syncthreads();
  }
  if (t == 0) part[b] = sm[0];
}

__global__ void k_scanB(int* __restrict__ part) {  // 128 threads
  __shared__ int sm[128];
  int t = threadIdx.x;
  int v = (t < NCHUNK) ? part[t] : 0;
  sm[t] = v; __syncthreads();
  for (int off = 1; off < 128; off <<= 1) {
    int x = (t >= off) ? sm[t - off] : 0;
    __syncthreads();
    sm[t] += x;
    __syncthreads();
  }
  if (t < NCHUNK) part[t] = sm[t] - v;  // exclusive
}

// scanC + dinv fused
__global__ __launch_bounds__(256) void k_scanC(const int* __restrict__ deg, const int* __restrict__ part,
                                               int* __restrict__ row_start, int* __restrict__ pos,
                                               float* __restrict__ dinv) {
  __shared__ int sm[256];
  int b = blockIdx.x, t = threadIdx.x;
  int base = b * SCAN_CHUNK + t * 4;
  int v[4]; int s = 0;
#pragma unroll
  for (int j = 0; j < 4; ++j) { int idx = base + j; v[j] = (idx < NN) ? deg[idx] : 0; s += v[j]; }
  sm[t] = s; __syncthreads();
  for (int off = 1; off < 256; off <<= 1) {
    int x = (t >= off) ? sm[t - off] : 0;
    __syncthreads();
    sm[t] += x;
    __syncthreads();
  }
  int excl = sm[t] - s + part[b];
#pragma unroll
  for (int j = 0; j < 4; ++j) {
    int idx = base + j;
    if (idx < NN) {
      row_start[idx] = excl; pos[idx] = excl; excl += v[j];
      dinv[idx] = rsqrtf((float)v[j] + 1.0f);   // +1 self loop
    }
  }
  if (b == 0 && t == 0) row_start[NN] = NE;
}

__global__ __launch_bounds__(256) void k_csr_fill(const int* __restrict__ ei, int* __restrict__ pos,
                                                  int* __restrict__ csr_src) {
  int e = blockIdx.x * 256 + threadIdx.x;
  if (e >= NE) return;
  int d = ei[NE + e];
  int slot = atomicAdd(&pos[d], 1);
  csr_src[slot] = ei[e];
}

// ---------------- merged prep: gstart | conv_W cvt | lin0_W cvt | lin1_W cvt ----------------
#define MB_GS   391
#define MB_WC   768
#define MB_W0C  64
#define MB_W1C  256
__global__ __launch_bounds__(256) void k_misc(const int* __restrict__ batch, int* __restrict__ gstart,
                                              const float* __restrict__ convW, ushort* __restrict__ Whi,
                                              ushort* __restrict__ Wlo,
                                              const float* __restrict__ lin0W, ushort* __restrict__ W0hi,
                                              ushort* __restrict__ W0lo,
                                              const float* __restrict__ W1, ushort* __restrict__ W1hi,
                                              ushort* __restrict__ W1lo) {
  int b = blockIdx.x, t = threadIdx.x;
  if (b < MB_GS) {
    int i = b * 256 + t;
    if (i >= NN) return;
    int bb = batch[i];
    int pb = (i == 0) ? -1 : batch[i - 1];
    for (int g = pb + 1; g <= bb; ++g) gstart[g] = i;
    if (i == NN - 1) {
      for (int g = bb + 1; g <= NG; ++g) gstart[g] = NN;
    }
  } else if (b < MB_GS + MB_WC) {
    int i = (b - MB_GS) * 256 + t;               // < 3*HID*HID
    ushort h, l; splitbf(convW[i], h, l);
    Whi[i] = h; Wlo[i] = l;
  } else if (b < MB_GS + MB_WC + MB_W0C) {
    int i = (b - MB_GS - MB_WC) * 256 + t;       // over 256*64
    int row = i >> 6, k = i & 63;
    float v = (k < CIN) ? lin0W[row * CIN + k] : 0.f;
    ushort h, l; splitbf(v, h, l);
    W0hi[i] = h; W0lo[i] = l;
  } else {
    int i = (b - MB_GS - MB_WC - MB_W0C) * 256 + t;   // over 256*256
    ushort h, l; splitbf(W1[i], h, l);
    W1hi[i] = h; W1lo[i] = l;
  }
}

#define GBM 48   // 48-row tiles: LDS 48 KB -> 3 blocks/CU (24 waves/CU, 75% ceiling)

// ---------------- FUSED lin0 + conv0: T = (elu(x@W0^T+b0)) @ Wc^T ----------------
// 48-row tile, 8 waves; X tile overlays the A LDS (X dead after phase 1).
__global__ __launch_bounds__(512) void k_l0conv(const float* __restrict__ x,
                                                const ushort* __restrict__ W0hi, const ushort* __restrict__ W0lo,
                                                const float* __restrict__ bias0,
                                                const ushort* __restrict__ Wchi, const ushort* __restrict__ Wclo,
                                                float* __restrict__ T) {
  __shared__ ushort sAhi[GBM * HID];  // 24 KB (first 48*64 entries host X-hi in phase 0/1)
  __shared__ ushort sAlo[GBM * HID];  // 24 KB (likewise X-lo)
  int tid = threadIdx.x;
  int wave = tid >> 6, lane = tid & 63;
  int m0 = blockIdx.x * GBM;
  int n0 = wave * 32;                 // 32-col slice per wave
  int lr = lane & 15;
  int q  = lane >> 4;
  int kg = q * 8;

  // ---- phase 0: stage x tile (f32 -> bf16 hi/lo, swizzled) into sA* head ----
  if (tid < GBM * 8) {
    int row = tid >> 3;               // 0..47
    int c0 = (tid & 7) * 8;           // 0..56
    int grow = m0 + row;
    int key = (row & 7) << 3;
    int idx = row * KPAD + (c0 ^ key);
#pragma unroll
    for (int j = 0; j < 8; ++j) {
      int c = c0 + j;
      float v = (grow < NN && c < CIN) ? x[(size_t)grow * CIN + c] : 0.f;
      ushort h, l; splitbf(v, h, l);
      sAhi[idx + j] = h;
      sAlo[idx + j] = l;
    }
  }
  __syncthreads();

  f32x4 acc[3][2];
#pragma unroll
  for (int i = 0; i < 3; ++i)
#pragma unroll
    for (int j = 0; j < 2; ++j) { acc[i][j].x = 0.f; acc[i][j].y = 0.f; acc[i][j].z = 0.f; acc[i][j].w = 0.f; }

  // ---- phase 1: A = elu(X @ W0^T + b0), X from LDS head ----
#pragma unroll
  for (int k0 = 0; k0 < KPAD; k0 += 32) {
    bf16x8 ah[3], al[3], bh[2], bl[2];
#pragma unroll
    for (int i = 0; i < 3; ++i) {
      int row = i * 16 + lr;
      int kk = (k0 + kg) ^ ((row & 7) << 3);
      ah[i] = *(const bf16x8*)&sAhi[row * KPAD + kk];
      al[i] = *(const bf16x8*)&sAlo[row * KPAD + kk];
    }
#pragma unroll
    for (int j = 0; j < 2; ++j) {
      int col = n0 + j * 16 + lr;
      bh[j] = *(const bf16x8*)(W0hi + (size_t)col * KPAD + k0 + kg);
      bl[j] = *(const bf16x8*)(W0lo + (size_t)col * KPAD + k0 + kg);
    }
#pragma unroll
    for (int i = 0; i < 3; ++i)
#pragma unroll
      for (int j = 0; j < 2; ++j) {
        acc[i][j] = __builtin_amdgcn_mfma_f32_16x16x32_bf16(ah[i], bh[j], acc[i][j], 0, 0, 0);
        acc[i][j] = __builtin_amdgcn_mfma_f32_16x16x32_bf16(ah[i], bl[j], acc[i][j], 0, 0, 0);
        acc[i][j] = __builtin_amdgcn_mfma_f32_16x16x32_bf16(al[i], bh[j], acc[i][j], 0, 0, 0);
      }
  }
  __syncthreads();   // X reads done -> safe to overwrite sA* with the A tile

  // ---- epilogue: bias + ELU + split -> separate hi/lo LDS (swzk key) ----
  float bb[2];
#pragma unroll
  for (int j = 0; j < 2; ++j) bb[j] = bias0[n0 + j * 16 + lr];
  // C/D: col = lane&15, row = (lane>>4)*4 + reg
#pragma unroll
  for (int i = 0; i < 3; ++i) {
#pragma unroll
    for (int r = 0; r < 4; ++r) {
      int row = i * 16 + q * 4 + r;             // local row 0..47
      int key = (row & 7) << 3;                 // ushort-index XOR key
#pragma unroll
      for (int j = 0; j < 2; ++j) {
        int col = n0 + j * 16 + lr;
        float v = acc[i][j][r] + bb[j];
        v = v > 0.f ? v : __expf(v) - 1.f;      // ELU (fast path)
        ushort h, l; splitbf(v, h, l);
        int idx = row * HID + (col ^ key);
        sAhi[idx] = h;
        sAlo[idx] = l;
      }
    }
  }
  __syncthreads();

  // ---- phase 2: T = A @ Wc^T, A from LDS (direct bf16x8), W dbuf from L2 ----
#pragma unroll
  for (int i = 0; i < 3; ++i)
#pragma unroll
    for (int j = 0; j < 2; ++j) { acc[i][j].x = 0.f; acc[i][j].y = 0.f; acc[i][j].z = 0.f; acc[i][j].w = 0.f; }

  const ushort* pWh[2]; const ushort* pWl[2];
#pragma unroll
  for (int j = 0; j < 2; ++j) {
    int col = n0 + j * 16 + lr;
    pWh[j] = Wchi + (size_t)col * HID + kg;
    pWl[j] = Wclo + (size_t)col * HID + kg;
  }
  bf16x8 bhc[2], blc[2];
#pragma unroll
  for (int j = 0; j < 2; ++j) { bhc[j] = *(const bf16x8*)pWh[j]; blc[j] = *(const bf16x8*)pWl[j]; }

#pragma unroll 1
  for (int k0 = 0; k0 < HID; k0 += 32) {
    int k1 = (k0 + 32 < HID) ? k0 + 32 : 0;
    bf16x8 bhn[2], bln[2];
#pragma unroll
    for (int j = 0; j < 2; ++j) {       // issue next-step W loads first
      bhn[j] = *(const bf16x8*)(pWh[j] + k1);
      bln[j] = *(const bf16x8*)(pWl[j] + k1);
    }
    bf16x8 ah[3], al[3];
#pragma unroll
    for (int i = 0; i < 3; ++i) {       // A from LDS, unpack-free
      int row = i * 16 + lr;
      int kk = swzk(row, k0 + kg);
      ah[i] = *(const bf16x8*)&sAhi[row * HID + kk];
      al[i] = *(const bf16x8*)&sAlo[row * HID + kk];
    }
#pragma unroll
    for (int i = 0; i < 3; ++i)
#pragma unroll
      for (int j = 0; j < 2; ++j) {
        acc[i][j] = __builtin_amdgcn_mfma_f32_16x16x32_bf16(ah[i], bhc[j], acc[i][j], 0, 0, 0);
        acc[i][j] = __builtin_amdgcn_mfma_f32_16x16x32_bf16(ah[i], blc[j], acc[i][j], 0, 0, 0);
        acc[i][j] = __builtin_amdgcn_mfma_f32_16x16x32_bf16(al[i], bhc[j], acc[i][j], 0, 0, 0);
      }
#pragma unroll
    for (int j = 0; j < 2; ++j) { bhc[j] = bhn[j]; blc[j] = bln[j]; }
  }
  // write T  (C/D: col = lane&15, row = (lane>>4)*4 + reg)
#pragma unroll
  for (int i = 0; i < 3; ++i) {
#pragma unroll
    for (int r = 0; r < 4; ++r) {
      int row = m0 + i * 16 + q * 4 + r;
      if (row < NN) {
        float* cp = T + (size_t)row * HID + n0 + lr;
        cp[0]  = acc[i][0][r];
        cp[16] = acc[i][1][r];
      }
    }
  }
}

// ---------------- MFMA split-bf16 GEMM: C = A @ W^T ----------------
// 48-row tile, 8 waves, wave = 48x32 slice; full-K A hi+lo in LDS (48 KB).
__global__ __launch_bounds__(512) void k_gemm_mfma(const ushort* __restrict__ Ahi, const ushort* __restrict__ Alo,
                                                   const ushort* __restrict__ Whi, const ushort* __restrict__ Wlo,
                                                   float* __restrict__ C, int M) {
  __shared__ ushort sAhi[GBM * HID];   // 24 KB, linear copy of swizzled global
  __shared__ ushort sAlo[GBM * HID];   // 24 KB
  int tid = threadIdx.x;
  int wave = tid >> 6, lane = tid & 63;
  int m0 = blockIdx.x * GBM;
  int n0 = wave * 32;
  int lr = lane & 15;
  int q  = lane >> 4;
  int kg = q * 8;

  // ---- stage A tile: 24 segments x 1024 B per buffer, 3 per wave ----
  const ushort* gh = Ahi + (size_t)m0 * HID;
  const ushort* gl = Alo + (size_t)m0 * HID;
#pragma unroll
  for (int sgm = 0; sgm < 3; ++sgm) {
    int seg = sgm * 8 + wave;            // 0..23
    gload16(gh + seg * 512 + lane * 8, &sAhi[seg * 512]);
    gload16(gl + seg * 512 + lane * 8, &sAlo[seg * 512]);
  }

  const ushort* pWh[2]; const ushort* pWl[2];
#pragma unroll
  for (int j = 0; j < 2; ++j) {
    int col = n0 + j * 16 + lr;
    pWh[j] = Whi + (size_t)col * HID + kg;
    pWl[j] = Wlo + (size_t)col * HID + kg;
  }
  bf16x8 bhc[2], blc[2];
#pragma unroll
  for (int j = 0; j < 2; ++j) { bhc[j] = *(const bf16x8*)pWh[j]; blc[j] = *(const bf16x8*)pWl[j]; }

  __syncthreads();   // A tile ready

  f32x4 acc[3][2];
#pragma unroll
  for (int i = 0; i < 3; ++i)
#pragma unroll
    for (int j = 0; j < 2; ++j) { acc[i][j].x = 0.f; acc[i][j].y = 0.f; acc[i][j].z = 0.f; acc[i][j].w = 0.f; }

#pragma unroll 1
  for (int k0 = 0; k0 < HID; k0 += 32) {
    int k1 = (k0 + 32 < HID) ? k0 + 32 : 0;
    bf16x8 bhn[2], bln[2];
#pragma unroll
    for (int j = 0; j < 2; ++j) {       // issue next-step W loads first
      bhn[j] = *(const bf16x8*)(pWh[j] + k1);
      bln[j] = *(const bf16x8*)(pWl[j] + k1);
    }
    bf16x8 ah[3], al[3];
#pragma unroll
    for (int i = 0; i < 3; ++i) {
      int row = i * 16 + lr;
      int kk = swzk(row, k0 + kg);
      ah[i] = *(const bf16x8*)&sAhi[row * HID + kk];
      al[i] = *(const bf16x8*)&sAlo[row * HID + kk];
    }
#pragma unroll
    for (int i = 0; i < 3; ++i)
#pragma unroll
      for (int j = 0; j < 2; ++j) {
        acc[i][j] = __builtin_amdgcn_mfma_f32_16x16x32_bf16(ah[i], bhc[j], acc[i][j], 0, 0, 0);
        acc[i][j] = __builtin_amdgcn_mfma_f32_16x16x32_bf16(ah[i], blc[j], acc[i][j], 0, 0, 0);
        acc[i][j] = __builtin_amdgcn_mfma_f32_16x16x32_bf16(al[i], bhc[j], acc[i][j], 0, 0, 0);
      }
#pragma unroll
    for (int j = 0; j < 2; ++j) { bhc[j] = bhn[j]; blc[j] = bln[j]; }
  }
#pragma unroll
  for (int i = 0; i < 3; ++i) {
#pragma unroll
    for (int r = 0; r < 4; ++r) {
      int row = m0 + i * 16 + q * 4 + r;
      if (row < M) {
        float* cp = C + (size_t)row * HID + n0 + lr;
        cp[0]  = acc[i][0][r];
        cp[16] = acc[i][1][r];
      }
    }
  }
}

// ---------------- aggregate: one wave per dst node, 4-wide edge pipeline ----------------
// XCD-aware block swizzle (T1): 25000 blocks = 8 * 3125 exactly -> bijective.
__global__ __launch_bounds__(256) void k_aggregate(const float* __restrict__ T, const float* __restrict__ dinv,
                                                   const int* __restrict__ row_start, const int* __restrict__ csr_src,
                                                   const float* __restrict__ bias,
                                                   ushort* __restrict__ Ahi, ushort* __restrict__ Alo) {
  int bid = blockIdx.x;
  int sbid = (bid & 7) * 3125 + (bid >> 3);   // XCD chunking
  int wid = sbid * 4 + (threadIdx.x >> 6);
  int lane = threadIdx.x & 63;
  if (wid >= NN) return;
  float di = dinv[wid];
  int s = row_start[wid], e = row_start[wid + 1];
  float4 acc = make_float4(0.f, 0.f, 0.f, 0.f);
  for (int t0 = s; t0 < e; t0 += 4) {
    int sj[4]; float cj[4];
#pragma unroll
    for (int j = 0; j < 4; ++j) {            // 4 index loads in flight
      int t = t0 + j;
      sj[j] = (t < e) ? csr_src[t] : wid;
    }
#pragma unroll
    for (int j = 0; j < 4; ++j) {            // 4 coef loads in flight
      int t = t0 + j;
      cj[j] = (t < e) ? dinv[sj[j]] * di : 0.f;
    }
    float4 r0 = ((const float4*)(T + (size_t)sj[0] * HID))[lane];
    float4 r1 = ((const float4*)(T + (size_t)sj[1] * HID))[lane];
    float4 r2 = ((const float4*)(T + (size_t)sj[2] * HID))[lane];
    float4 r3 = ((const float4*)(T + (size_t)sj[3] * HID))[lane];
    acc.x = fmaf(r0.x, cj[0], acc.x); acc.y = fmaf(r0.y, cj[0], acc.y);
    acc.z = fmaf(r0.z, cj[0], acc.z); acc.w = fmaf(r0.w, cj[0], acc.w);
    acc.x = fmaf(r1.x, cj[1], acc.x); acc.y = fmaf(r1.y, cj[1], acc.y);
    acc.z = fmaf(r1.z, cj[1], acc.z); acc.w = fmaf(r1.w, cj[1], acc.w);
    acc.x = fmaf(r2.x, cj[2], acc.x); acc.y = fmaf(r2.y, cj[2], acc.y);
    acc.z = fmaf(r2.z, cj[2], acc.z); acc.w = fmaf(r2.w, cj[2], acc.w);
    acc.x = fmaf(r3.x, cj[3], acc.x); acc.y = fmaf(r3.y, cj[3], acc.y);
    acc.z = fmaf(r3.z, cj[3], acc.z); acc.w = fmaf(r3.w, cj[3], acc.w);
  }
  float4 v = ((const float4*)(T + (size_t)wid * HID))[lane];
  float sc = di * di;
  float4 bb = ((const float4*)bias)[lane];
  acc.x = fmaf(v.x, sc, acc.x) + bb.x;
  acc.y = fmaf(v.y, sc, acc.y) + bb.y;
  acc.z = fmaf(v.z, sc, acc.z) + bb.z;
  acc.w = fmaf(v.w, sc, acc.w) + bb.w;
  ushort4 h4, l4;
  splitbf(acc.x, h4.x, l4.x); splitbf(acc.y, h4.y, l4.y);
  splitbf(acc.z, h4.z, l4.z); splitbf(acc.w, h4.w, l4.w);
  int kc = swzk(wid, lane * 4);
  *(ushort4*)(Ahi + (size_t)wid * HID + kc) = h4;
  *(ushort4*)(Alo + (size_t)wid * HID + kc) = l4;
}

// ---------------- GraphNorm (+ReLU; last layer pools into swizzled bf16 hi/lo) ----------------
__global__ __launch_bounds__(256) void k_gnorm(ushort* __restrict__ Ahi, ushort* __restrict__ Alo,
                                               const int* __restrict__ gstart,
                                               const float* __restrict__ alpha, const float* __restrict__ gamma,
                                               const float* __restrict__ beta,
                                               ushort* __restrict__ Phi, ushort* __restrict__ Plo,
                                               int last) {
  __shared__ float4 smA[4][64];
  __shared__ float4 smB[4][64];
  int g = blockIdx.x;
  int r = threadIdx.x >> 6;        // 0..3
  int cg = threadIdx.x & 63;       // channel group
  int c0 = cg * 4;
  int s = gstart[g], e = gstart[g + 1];
  int n = e - s;
  float cnt = (float)(n > 1 ? n : 1);
  float s1[4] = {0.f, 0.f, 0.f, 0.f}, s2[4] = {0.f, 0.f, 0.f, 0.f};
  for (int i = s + r; i < e; i += 4) {
    int kc = swzk(i, c0);
    ushort4 h = *(const ushort4*)(Ahi + (size_t)i * HID + kc);
    ushort4 l = *(const ushort4*)(Alo + (size_t)i * HID + kc);
    float v0 = joinbf(h.x, l.x), v1 = joinbf(h.y, l.y), v2 = joinbf(h.z, l.z), v3 = joinbf(h.w, l.w);
    s1[0] += v0; s2[0] = fmaf(v0, v0, s2[0]);
    s1[1] += v1; s2[1] = fmaf(v1, v1, s2[1]);
    s1[2] += v2; s2[2] = fmaf(v2, v2, s2[2]);
    s1[3] += v3; s2[3] = fmaf(v3, v3, s2[3]);
  }
  smA[r][cg] = make_float4(s1[0], s1[1], s1[2], s1[3]);
  smB[r][cg] = make_float4(s2[0], s2[1], s2[2], s2[3]);
  __syncthreads();
  float4 a0 = smA[0][cg], a1 = smA[1][cg], a2 = smA[2][cg], a3 = smA[3][cg];
  float4 b0 = smB[0][cg], b1 = smB[1][cg], b2 = smB[2][cg], b3 = smB[3][cg];
  float t1[4] = {a0.x + a1.x + a2.x + a3.x, a0.y + a1.y + a2.y + a3.y,
                 a0.z + a1.z + a2.z + a3.z, a0.w + a1.w + a2.w + a3.w};
  float t2[4] = {b0.x + b1.x + b2.x + b3.x, b0.y + b1.y + b2.y + b3.y,
                 b0.z + b1.z + b2.z + b3.z, b0.w + b1.w + b2.w + b3.w};
  float4 al4 = *(const float4*)(alpha + c0);
  float4 ga4 = *(const float4*)(gamma + c0);
  float4 be4 = *(const float4*)(beta + c0);
  float am[4], rs[4];
  float alv[4] = {al4.x, al4.y, al4.z, al4.w};
  float gav[4] = {ga4.x, ga4.y, ga4.z, ga4.w};
  float bev[4] = {be4.x, be4.y, be4.z, be4.w};
#pragma unroll
  for (int j = 0; j < 4; ++j) {
    float mean = t1[j] / cnt;
    float a = alv[j] * mean;
    float var = t2[j] / cnt - 2.f * a * mean + a * a;
    am[j] = a;
    rs[j] = rsqrtf(var + EPSV) * gav[j];
  }
  if (last) {
    float p[4] = {0.f, 0.f, 0.f, 0.f};
    for (int i = s + r; i < e; i += 4) {
      int kc = swzk(i, c0);
      ushort4 h = *(const ushort4*)(Ahi + (size_t)i * HID + kc);
      ushort4 l = *(const ushort4*)(Alo + (size_t)i * HID + kc);
      float v[4] = {joinbf(h.x, l.x), joinbf(h.y, l.y), joinbf(h.z, l.z), joinbf(h.w, l.w)};
#pragma unroll
      for (int j = 0; j < 4; ++j) p[j] += fmaxf((v[j] - am[j]) * rs[j] + bev[j], 0.f);
    }
    __syncthreads();   // WAR on smA
    smA[r][cg] = make_float4(p[0], p[1], p[2], p[3]);
    __syncthreads();
    if (r == 0) {
      float4 p0 = smA[0][cg], p1 = smA[1][cg], p2 = smA[2][cg], p3 = smA[3][cg];
      float tp[4] = {p0.x + p1.x + p2.x + p3.x, p0.y + p1.y + p2.y + p3.y,
                     p0.z + p1.z + p2.z + p3.z, p0.w + p1.w + p2.w + p3.w};
      ushort4 h4, l4;
      splitbf(tp[0], h4.x, l4.x); splitbf(tp[1], h4.y, l4.y);
      splitbf(tp[2], h4.z, l4.z); splitbf(tp[3], h4.w, l4.w);
      int kc = swzk(g, c0);
      *(ushort4*)(Phi + (size_t)g * HID + kc) = h4;
      *(ushort4*)(Plo + (size_t)g * HID + kc) = l4;
    }
  } else {
    for (int i = s + r; i < e; i += 4) {
      int kc = swzk(i, c0);
      ushort4 h = *(const ushort4*)(Ahi + (size_t)i * HID + kc);
      ushort4 l = *(const ushort4*)(Alo + (size_t)i * HID + kc);
      float v[4] = {joinbf(h.x, l.x), joinbf(h.y, l.y), joinbf(h.z, l.z), joinbf(h.w, l.w)};
      ushort4 ho, lo4;
      float o0 = fmaxf((v[0] - am[0]) * rs[0] + bev[0], 0.f);
      float o1 = fmaxf((v[1] - am[1]) * rs[1] + bev[1], 0.f);
      float o2 = fmaxf((v[2] - am[2]) * rs[2] + bev[2], 0.f);
      float o3 = fmaxf((v[3] - am[3]) * rs[3] + bev[3], 0.f);
      splitbf(o0, ho.x, lo4.x); splitbf(o1, ho.y, lo4.y);
      splitbf(o2, ho.z, lo4.z); splitbf(o3, ho.w, lo4.w);
      *(ushort4*)(Ahi + (size_t)i * HID + kc) = ho;
      *(ushort4*)(Alo + (size_t)i * HID + kc) = lo4;
    }
  }
}

// ---------------- head epilogue: relu(H2+b1) . Wout -> sigmoid ----------------
__global__ __launch_bounds__(256) void k_head2(const float* __restrict__ H2, const float* __restrict__ b1,
                                               const float* __restrict__ Wout, const float* __restrict__ bout,
                                               float* __restrict__ out) {
  int g0 = blockIdx.x * 4, t = threadIdx.x;
  __shared__ float red[4][HID];
  float b = b1[t];
  float wo = Wout[t];
#pragma unroll
  for (int gg = 0; gg < 4; ++gg) {
    float v = H2[(size_t)(g0 + gg) * HID + t] + b;
    red[gg][t] = fmaxf(v, 0.f) * wo;
  }
  __syncthreads();
  for (int off = 128; off > 0; off >>= 1) {
    if (t < off) {
#pragma unroll
      for (int gg = 0; gg < 4; ++gg) red[gg][t] += red[gg][t + off];
    }
    __syncthreads();
  }
  if (t < 4) out[g0 + t] = 1.f / (1.f + __expf(-(red[t][0] + bout[0])));
}

// ---------------- launch ----------------
extern "C" void kernel_launch(void* const* d_in, const int* in_sizes, int n_in,
                              void* d_out, int out_size, void* d_ws, size_t ws_size,
                              hipStream_t stream) {
  const float* x          = (const float*)d_in[0];
  const int*   edge_index = (const int*)d_in[1];
  const int*   batch      = (const int*)d_in[2];
  const float* lin0_W     = (const float*)d_in[3];
  const float* lin0_b     = (const float*)d_in[4];
  const float* conv_W     = (const float*)d_in[5];
  const float* conv_b     = (const float*)d_in[6];
  const float* n_alpha    = (const float*)d_in[7];
  const float* n_gamma    = (const float*)d_in[8];
  const float* n_beta     = (const float*)d_in[9];
  const float* lin1_W     = (const float*)d_in[10];
  const float* lin1_b     = (const float*)d_in[11];
  const float* out_W      = (const float*)d_in[12];
  const float* out_b      = (const float*)d_in[13];
  float* out = (float*)d_out;

  char* ws = (char*)d_ws;
  size_t off = 0;
  auto nxt = [&](size_t bytes) { size_t o = off; off += (bytes + 255) & ~(size_t)255; return o; };
  ushort* Ahi    = (ushort*)(ws + nxt((size_t)NN * HID * 2));
  ushort* Alo    = (ushort*)(ws + nxt((size_t)NN * HID * 2));
  float*  Tbuf   = (float*) (ws + nxt((size_t)NN * HID * 4));   // also head GEMM output
  float*  dinv   = (float*) (ws + nxt((size_t)NN * 4));
  int*    deg    = (int*)   (ws + nxt((size_t)NN * 4));
  int*    rstart = (int*)   (ws + nxt((size_t)(NN + 1) * 4));
  int*    csrsrc = (int*)   (ws + nxt((size_t)NE * 4));
  int*    gstart = (int*)   (ws + nxt((size_t)(NG + 1) * 4));
  char*   poolbase = ws + nxt((size_t)NG * HID * 4);       // 2,048,000 B block, sub-carved:
  int*    pos    = (int*)(poolbase);                        //   [0, 400000) dead after csr_fill
  ushort* Whi    = (ushort*)(poolbase + 400384);            //   dead after last layer gemm
  ushort* Wlo    = (ushort*)(poolbase + 793600);
  ushort* W1hi   = (ushort*)(ws + nxt((size_t)HID * HID * 2));
  ushort* W1lo   = (ushort*)(ws + nxt((size_t)HID * HID * 2));
  ushort* W0hi   = (ushort*)(ws + nxt((size_t)HID * KPAD * 2));
  ushort* W0lo   = (ushort*)(ws + nxt((size_t)HID * KPAD * 2));
  ushort* Phi    = (ushort*)(ws + nxt((size_t)2048 * HID * 2));  // pooled hi (2048-row padded)
  ushort* Plo    = (ushort*)(ws + nxt((size_t)2048 * HID * 2));  // pooled lo
  int*    part   = (int*)   (ws + nxt((size_t)NCHUNK * 4));
  (void)ws_size; (void)in_sizes; (void)n_in; (void)out_size;

  hipMemsetAsync(deg, 0, (size_t)NN * 4, stream);
  k_deg<<<(NE + 255) / 256, 256, 0, stream>>>(edge_index, deg);
  k_scanA<<<NCHUNK, 256, 0, stream>>>(deg, part);
  k_scanB<<<1, 128, 0, stream>>>(part);
  k_scanC<<<NCHUNK, 256, 0, stream>>>(deg, part, rstart, pos, dinv);
  k_csr_fill<<<(NE + 255) / 256, 256, 0, stream>>>(edge_index, pos, csrsrc);
  k_misc<<<MB_GS + MB_WC + MB_W0C + MB_W1C, 256, 0, stream>>>(batch, gstart, conv_W, Whi, Wlo,
                                                              lin0_W, W0hi, W0lo, lin1_W, W1hi, W1lo);

  // fused lin0 + conv0 -> Tbuf  (x staged in-kernel; A never hits global)
  k_l0conv<<<(NN + GBM - 1) / GBM, 512, 0, stream>>>(x, W0hi, W0lo, lin0_b, Whi, Wlo, Tbuf);

  for (int l = 0; l < 3; ++l) {
    if (l > 0)
      k_gemm_mfma<<<(NN + GBM - 1) / GBM, 512, 0, stream>>>(
          Ahi, Alo, Whi + (size_t)l * HID * HID, Wlo + (size_t)l * HID * HID, Tbuf, NN);
    k_aggregate<<<(NN + 3) / 4, 256, 0, stream>>>(Tbuf, dinv, rstart, csrsrc, conv_b + l * HID, Ahi, Alo);
    k_gnorm<<<NG, 256, 0, stream>>>(Ahi, Alo, gstart, n_alpha + l * HID, n_gamma + l * HID, n_beta + l * HID,
                                    Phi, Plo, l == 2 ? 1 : 0);
  }
  // head: pooled(bf16 hi/lo) @ W1^T via MFMA, then bias+relu+dot+sigmoid
  k_gemm_mfma<<<(NG + GBM - 1) / GBM, 512, 0, stream>>>(Phi, Plo, W1hi, W1lo, Tbuf, NG);
  k_head2<<<NG / 4, 256, 0, stream>>>(Tbuf, lin1_b, out_W, out_b, out);
}

// Round 17
// 629.107 us; speedup vs baseline: 1.0567x; 1.0567x over previous
//
#include <hip/hip_runtime.h>
#include <math.h>

#define NN 100000   // nodes
#define NE 300000   // edges
#define NG 2000     // graphs
#define HID 256
#define CIN 59
#define KPAD 64     // CIN padded to MFMA K
#define EPSV 1e-5f

#define SCAN_CHUNK 1024
#define NCHUNK ((NN + SCAN_CHUNK - 1) / SCAN_CHUNK)   // 98

typedef __attribute__((ext_vector_type(8))) short bf16x8;   // 8 bf16 (4 VGPRs)
typedef __attribute__((ext_vector_type(4))) float f32x4;

// Activations (and pooled) live in a row-swizzled global layout: element
// (r,k) at ushort index r*HID + (k ^ ((r&7)<<3)).  Linear global->LDS copy
// then yields conflict-free ds_read_b128 in the GEMM.
__device__ __forceinline__ int swzk(int row, int k) { return k ^ ((row & 7) << 3); }

// ---------- f32 -> (bf16 hi, bf16 lo) split, round-to-nearest ----------
__device__ inline void splitbf(float x, ushort& hi, ushort& lo) {
  union { float f; unsigned u; } a; a.f = x;
  unsigned r = a.u + 0x7FFFu + ((a.u >> 16) & 1u);
  hi = (ushort)(r >> 16);
  union { unsigned u; float f; } h; h.u = (unsigned)hi << 16;
  union { float f; unsigned u; } d; d.f = x - h.f;
  unsigned r2 = d.u + 0x7FFFu + ((d.u >> 16) & 1u);
  lo = (ushort)(r2 >> 16);
}
__device__ inline float joinbf(ushort hi, ushort lo) {
  union { unsigned u; float f; } a, b;
  a.u = (unsigned)hi << 16; b.u = (unsigned)lo << 16;
  return a.f + b.f;
}

__device__ __forceinline__ void gload16(const ushort* g, ushort* l) {
  __builtin_amdgcn_global_load_lds(
      (const __attribute__((address_space(1))) unsigned int*)g,
      (__attribute__((address_space(3))) unsigned int*)l, 16, 0, 0);
}

// ---------------- degree / CSR build ----------------

__global__ __launch_bounds__(256) void k_deg(const int* __restrict__ ei, int* __restrict__ deg) {
  int e = blockIdx.x * 256 + threadIdx.x;
  if (e < NE) atomicAdd(&deg[ei[NE + e]], 1);   // dst = ei[1][e]
}

__global__ __launch_bounds__(256) void k_scanA(const int* __restrict__ deg, int* __restrict__ part) {
  __shared__ int sm[256];
  int b = blockIdx.x, t = threadIdx.x;
  int base = b * SCAN_CHUNK + t * 4;
  int s = 0;
#pragma unroll
  for (int j = 0; j < 4; ++j) { int idx = base + j; if (idx < NN) s += deg[idx]; }
  sm[t] = s; __syncthreads();
  for (int off = 128; off > 0; off >>= 1) {
    if (t < off) sm[t] += sm[t + off];
    __syncthreads();
  }
  if (t == 0) part[b] = sm[0];
}

__global__ void k_scanB(int* __restrict__ part) {  // 128 threads
  __shared__ int sm[128];
  int t = threadIdx.x;
  int v = (t < NCHUNK) ? part[t] : 0;
  sm[t] = v; __syncthreads();
  for (int off = 1; off < 128; off <<= 1) {
    int x = (t >= off) ? sm[t - off] : 0;
    __syncthreads();
    sm[t] += x;
    __syncthreads();
  }
  if (t < NCHUNK) part[t] = sm[t] - v;  // exclusive
}

// scanC + dinv fused
__global__ __launch_bounds__(256) void k_scanC(const int* __restrict__ deg, const int* __restrict__ part,
                                               int* __restrict__ row_start, int* __restrict__ pos,
                                               float* __restrict__ dinv) {
  __shared__ int sm[256];
  int b = blockIdx.x, t = threadIdx.x;
  int base = b * SCAN_CHUNK + t * 4;
  int v[4]; int s = 0;
#pragma unroll
  for (int j = 0; j < 4; ++j) { int idx = base + j; v[j] = (idx < NN) ? deg[idx] : 0; s += v[j]; }
  sm[t] = s; __syncthreads();
  for (int off = 1; off < 256; off <<= 1) {
    int x = (t >= off) ? sm[t - off] : 0;
    __syncthreads();
    sm[t] += x;
    __syncthreads();
  }
  int excl = sm[t] - s + part[b];
#pragma unroll
  for (int j = 0; j < 4; ++j) {
    int idx = base + j;
    if (idx < NN) {
      row_start[idx] = excl; pos[idx] = excl; excl += v[j];
      dinv[idx] = rsqrtf((float)v[j] + 1.0f);   // +1 self loop
    }
  }
  if (b == 0 && t == 0) row_start[NN] = NE;
}

__global__ __launch_bounds__(256) void k_csr_fill(const int* __restrict__ ei, int* __restrict__ pos,
                                                  int* __restrict__ csr_src) {
  int e = blockIdx.x * 256 + threadIdx.x;
  if (e >= NE) return;
  int d = ei[NE + e];
  int slot = atomicAdd(&pos[d], 1);
  csr_src[slot] = ei[e];
}

// ---------------- merged prep: gstart | conv_W cvt | lin0_W cvt | lin1_W cvt ----------------
#define MB_GS   391
#define MB_WC   768
#define MB_W0C  64
#define MB_W1C  256
__global__ __launch_bounds__(256) void k_misc(const int* __restrict__ batch, int* __restrict__ gstart,
                                              const float* __restrict__ convW, ushort* __restrict__ Whi,
                                              ushort* __restrict__ Wlo,
                                              const float* __restrict__ lin0W, ushort* __restrict__ W0hi,
                                              ushort* __restrict__ W0lo,
                                              const float* __restrict__ W1, ushort* __restrict__ W1hi,
                                              ushort* __restrict__ W1lo) {
  int b = blockIdx.x, t = threadIdx.x;
  if (b < MB_GS) {
    int i = b * 256 + t;
    if (i >= NN) return;
    int bb = batch[i];
    int pb = (i == 0) ? -1 : batch[i - 1];
    for (int g = pb + 1; g <= bb; ++g) gstart[g] = i;
    if (i == NN - 1) {
      for (int g = bb + 1; g <= NG; ++g) gstart[g] = NN;
    }
  } else if (b < MB_GS + MB_WC) {
    int i = (b - MB_GS) * 256 + t;               // < 3*HID*HID
    ushort h, l; splitbf(convW[i], h, l);
    Whi[i] = h; Wlo[i] = l;
  } else if (b < MB_GS + MB_WC + MB_W0C) {
    int i = (b - MB_GS - MB_WC) * 256 + t;       // over 256*64
    int row = i >> 6, k = i & 63;
    float v = (k < CIN) ? lin0W[row * CIN + k] : 0.f;
    ushort h, l; splitbf(v, h, l);
    W0hi[i] = h; W0lo[i] = l;
  } else {
    int i = (b - MB_GS - MB_WC - MB_W0C) * 256 + t;   // over 256*256
    ushort h, l; splitbf(W1[i], h, l);
    W1hi[i] = h; W1lo[i] = l;
  }
}

// ---------------- FUSED lin0 + conv0: T = (elu(x@W0^T+b0)) @ Wc^T ----------------
// 64-row tile, 8 waves; X staged once (f32 -> swizzled bf16 hi/lo LDS, 16 KB).
__global__ __launch_bounds__(512) void k_l0conv(const float* __restrict__ x,
                                                const ushort* __restrict__ W0hi, const ushort* __restrict__ W0lo,
                                                const float* __restrict__ bias0,
                                                const ushort* __restrict__ Wchi, const ushort* __restrict__ Wclo,
                                                float* __restrict__ T) {
  __shared__ ushort sAhi[64 * HID];   // 32 KB
  __shared__ ushort sAlo[64 * HID];   // 32 KB
  __shared__ ushort sXhi[64 * KPAD];  // 8 KB
  __shared__ ushort sXlo[64 * KPAD];  // 8 KB
  int tid = threadIdx.x;
  int wave = tid >> 6, lane = tid & 63;
  int m0 = blockIdx.x * 64;
  int n0 = wave * 32;                 // 32-col slice per wave
  int lr = lane & 15;
  int q  = lane >> 4;
  int kg = q * 8;

  // ---- phase 0: stage x tile (f32 -> bf16 hi/lo, swizzled) ----
  {
    int row = tid >> 3;               // 0..63
    int c0 = (tid & 7) * 8;           // 0..56
    int grow = m0 + row;
    int key = (row & 7) << 3;
    int idx = row * KPAD + (c0 ^ key);
#pragma unroll
    for (int j = 0; j < 8; ++j) {
      int c = c0 + j;
      float v = (grow < NN && c < CIN) ? x[(size_t)grow * CIN + c] : 0.f;
      ushort h, l; splitbf(v, h, l);
      sXhi[idx + j] = h;
      sXlo[idx + j] = l;
    }
  }
  __syncthreads();

  f32x4 acc[4][2];
#pragma unroll
  for (int i = 0; i < 4; ++i)
#pragma unroll
    for (int j = 0; j < 2; ++j) { acc[i][j].x = 0.f; acc[i][j].y = 0.f; acc[i][j].z = 0.f; acc[i][j].w = 0.f; }

  // ---- phase 1: A = elu(X @ W0^T + b0), X from LDS ----
#pragma unroll
  for (int k0 = 0; k0 < KPAD; k0 += 32) {
    bf16x8 ah[4], al[4], bh[2], bl[2];
#pragma unroll
    for (int i = 0; i < 4; ++i) {
      int row = i * 16 + lr;
      int kk = (k0 + kg) ^ ((row & 7) << 3);
      ah[i] = *(const bf16x8*)&sXhi[row * KPAD + kk];
      al[i] = *(const bf16x8*)&sXlo[row * KPAD + kk];
    }
#pragma unroll
    for (int j = 0; j < 2; ++j) {
      int col = n0 + j * 16 + lr;
      bh[j] = *(const bf16x8*)(W0hi + (size_t)col * KPAD + k0 + kg);
      bl[j] = *(const bf16x8*)(W0lo + (size_t)col * KPAD + k0 + kg);
    }
#pragma unroll
    for (int i = 0; i < 4; ++i)
#pragma unroll
      for (int j = 0; j < 2; ++j) {
        acc[i][j] = __builtin_amdgcn_mfma_f32_16x16x32_bf16(ah[i], bh[j], acc[i][j], 0, 0, 0);
        acc[i][j] = __builtin_amdgcn_mfma_f32_16x16x32_bf16(ah[i], bl[j], acc[i][j], 0, 0, 0);
        acc[i][j] = __builtin_amdgcn_mfma_f32_16x16x32_bf16(al[i], bh[j], acc[i][j], 0, 0, 0);
      }
  }
  // ---- epilogue: bias + ELU + split -> separate hi/lo LDS (swzk key) ----
  float bb[2];
#pragma unroll
  for (int j = 0; j < 2; ++j) bb[j] = bias0[n0 + j * 16 + lr];
  // C/D: col = lane&15, row = (lane>>4)*4 + reg
#pragma unroll
  for (int i = 0; i < 4; ++i) {
#pragma unroll
    for (int r = 0; r < 4; ++r) {
      int row = i * 16 + q * 4 + r;             // local row 0..63
      int key = (row & 7) << 3;                 // ushort-index XOR key
#pragma unroll
      for (int j = 0; j < 2; ++j) {
        int col = n0 + j * 16 + lr;
        float v = acc[i][j][r] + bb[j];
        v = v > 0.f ? v : __expf(v) - 1.f;      // ELU (fast path)
        ushort h, l; splitbf(v, h, l);
        int idx = row * HID + (col ^ key);
        sAhi[idx] = h;
        sAlo[idx] = l;
      }
    }
  }
  __syncthreads();

  // ---- phase 2: T = A @ Wc^T, A from LDS (direct bf16x8), W dbuf from L2 ----
#pragma unroll
  for (int i = 0; i < 4; ++i)
#pragma unroll
    for (int j = 0; j < 2; ++j) { acc[i][j].x = 0.f; acc[i][j].y = 0.f; acc[i][j].z = 0.f; acc[i][j].w = 0.f; }

  const ushort* pWh[2]; const ushort* pWl[2];
#pragma unroll
  for (int j = 0; j < 2; ++j) {
    int col = n0 + j * 16 + lr;
    pWh[j] = Wchi + (size_t)col * HID + kg;
    pWl[j] = Wclo + (size_t)col * HID + kg;
  }
  bf16x8 bhc[2], blc[2];
#pragma unroll
  for (int j = 0; j < 2; ++j) { bhc[j] = *(const bf16x8*)pWh[j]; blc[j] = *(const bf16x8*)pWl[j]; }

#pragma unroll 1
  for (int k0 = 0; k0 < HID; k0 += 32) {
    int k1 = (k0 + 32 < HID) ? k0 + 32 : 0;
    bf16x8 bhn[2], bln[2];
#pragma unroll
    for (int j = 0; j < 2; ++j) {       // issue next-step W loads first
      bhn[j] = *(const bf16x8*)(pWh[j] + k1);
      bln[j] = *(const bf16x8*)(pWl[j] + k1);
    }
    bf16x8 ah[4], al[4];
#pragma unroll
    for (int i = 0; i < 4; ++i) {       // A from LDS, unpack-free
      int row = i * 16 + lr;
      int kk = swzk(row, k0 + kg);
      ah[i] = *(const bf16x8*)&sAhi[row * HID + kk];
      al[i] = *(const bf16x8*)&sAlo[row * HID + kk];
    }
#pragma unroll
    for (int i = 0; i < 4; ++i)
#pragma unroll
      for (int j = 0; j < 2; ++j) {
        acc[i][j] = __builtin_amdgcn_mfma_f32_16x16x32_bf16(ah[i], bhc[j], acc[i][j], 0, 0, 0);
        acc[i][j] = __builtin_amdgcn_mfma_f32_16x16x32_bf16(ah[i], blc[j], acc[i][j], 0, 0, 0);
        acc[i][j] = __builtin_amdgcn_mfma_f32_16x16x32_bf16(al[i], bhc[j], acc[i][j], 0, 0, 0);
      }
#pragma unroll
    for (int j = 0; j < 2; ++j) { bhc[j] = bhn[j]; blc[j] = bln[j]; }
  }
  // write T  (C/D: col = lane&15, row = (lane>>4)*4 + reg)
#pragma unroll
  for (int i = 0; i < 4; ++i) {
#pragma unroll
    for (int r = 0; r < 4; ++r) {
      int row = m0 + i * 16 + q * 4 + r;
      if (row < NN) {
        float* cp = T + (size_t)row * HID + n0 + lr;
        cp[0]  = acc[i][0][r];
        cp[16] = acc[i][1][r];
      }
    }
  }
}

// ---------------- MFMA split-bf16 GEMM: C = A @ W^T ----------------
// 64-row tile, 8 waves (512 thr), wave = 64x32 slice; full-K A hi+lo in LDS.
#define GBM 64
__global__ __launch_bounds__(512) void k_gemm_mfma(const ushort* __restrict__ Ahi, const ushort* __restrict__ Alo,
                                                   const ushort* __restrict__ Whi, const ushort* __restrict__ Wlo,
                                                   float* __restrict__ C, int M) {
  __shared__ ushort sAhi[GBM * HID];   // 32 KB, linear copy of swizzled global
  __shared__ ushort sAlo[GBM * HID];   // 32 KB
  int tid = threadIdx.x;
  int wave = tid >> 6, lane = tid & 63;
  int m0 = blockIdx.x * GBM;
  int n0 = wave * 32;
  int lr = lane & 15;
  int q  = lane >> 4;
  int kg = q * 8;

  // ---- stage A tile: 32 segments x 1024 B per buffer, 4 per wave ----
  const ushort* gh = Ahi + (size_t)m0 * HID;
  const ushort* gl = Alo + (size_t)m0 * HID;
#pragma unroll
  for (int sgm = 0; sgm < 4; ++sgm) {
    int seg = sgm * 8 + wave;            // 0..31
    gload16(gh + seg * 512 + lane * 8, &sAhi[seg * 512]);
    gload16(gl + seg * 512 + lane * 8, &sAlo[seg * 512]);
  }

  const ushort* pWh[2]; const ushort* pWl[2];
#pragma unroll
  for (int j = 0; j < 2; ++j) {
    int col = n0 + j * 16 + lr;
    pWh[j] = Whi + (size_t)col * HID + kg;
    pWl[j] = Wlo + (size_t)col * HID + kg;
  }
  bf16x8 bhc[2], blc[2];
#pragma unroll
  for (int j = 0; j < 2; ++j) { bhc[j] = *(const bf16x8*)pWh[j]; blc[j] = *(const bf16x8*)pWl[j]; }

  __syncthreads();   // A tile ready

  f32x4 acc[4][2];
#pragma unroll
  for (int i = 0; i < 4; ++i)
#pragma unroll
    for (int j = 0; j < 2; ++j) { acc[i][j].x = 0.f; acc[i][j].y = 0.f; acc[i][j].z = 0.f; acc[i][j].w = 0.f; }

#pragma unroll 1
  for (int k0 = 0; k0 < HID; k0 += 32) {
    int k1 = (k0 + 32 < HID) ? k0 + 32 : 0;
    bf16x8 bhn[2], bln[2];
#pragma unroll
    for (int j = 0; j < 2; ++j) {       // issue next-step W loads first
      bhn[j] = *(const bf16x8*)(pWh[j] + k1);
      bln[j] = *(const bf16x8*)(pWl[j] + k1);
    }
    bf16x8 ah[4], al[4];
#pragma unroll
    for (int i = 0; i < 4; ++i) {
      int row = i * 16 + lr;
      int kk = swzk(row, k0 + kg);
      ah[i] = *(const bf16x8*)&sAhi[row * HID + kk];
      al[i] = *(const bf16x8*)&sAlo[row * HID + kk];
    }
#pragma unroll
    for (int i = 0; i < 4; ++i)
#pragma unroll
      for (int j = 0; j < 2; ++j) {
        acc[i][j] = __builtin_amdgcn_mfma_f32_16x16x32_bf16(ah[i], bhc[j], acc[i][j], 0, 0, 0);
        acc[i][j] = __builtin_amdgcn_mfma_f32_16x16x32_bf16(ah[i], blc[j], acc[i][j], 0, 0, 0);
        acc[i][j] = __builtin_amdgcn_mfma_f32_16x16x32_bf16(al[i], bhc[j], acc[i][j], 0, 0, 0);
      }
#pragma unroll
    for (int j = 0; j < 2; ++j) { bhc[j] = bhn[j]; blc[j] = bln[j]; }
  }
#pragma unroll
  for (int i = 0; i < 4; ++i) {
#pragma unroll
    for (int r = 0; r < 4; ++r) {
      int row = m0 + i * 16 + q * 4 + r;
      if (row < M) {
        float* cp = C + (size_t)row * HID + n0 + lr;
        cp[0]  = acc[i][0][r];
        cp[16] = acc[i][1][r];
      }
    }
  }
}

// ---------------- aggregate: one wave per dst node (serial edge loop) ----------------
// XCD-aware block swizzle (T1): 25000 blocks = 8 * 3125 exactly -> bijective.
__global__ __launch_bounds__(256) void k_aggregate(const float* __restrict__ T, const float* __restrict__ dinv,
                                                   const int* __restrict__ row_start, const int* __restrict__ csr_src,
                                                   const float* __restrict__ bias,
                                                   ushort* __restrict__ Ahi, ushort* __restrict__ Alo) {
  int bid = blockIdx.x;
  int sbid = (bid & 7) * 3125 + (bid >> 3);   // XCD chunking
  int wid = sbid * 4 + (threadIdx.x >> 6);
  int lane = threadIdx.x & 63;
  if (wid >= NN) return;
  float di = dinv[wid];
  int s = row_start[wid], e = row_start[wid + 1];
  float4 acc = make_float4(0.f, 0.f, 0.f, 0.f);
  for (int t = s; t < e; ++t) {
    int src = csr_src[t];
    float c = dinv[src] * di;
    float4 v = ((const float4*)(T + (size_t)src * HID))[lane];
    acc.x = fmaf(v.x, c, acc.x); acc.y = fmaf(v.y, c, acc.y);
    acc.z = fmaf(v.z, c, acc.z); acc.w = fmaf(v.w, c, acc.w);
  }
  float4 v = ((const float4*)(T + (size_t)wid * HID))[lane];
  float sc = di * di;
  float4 bb = ((const float4*)bias)[lane];
  acc.x = fmaf(v.x, sc, acc.x) + bb.x;
  acc.y = fmaf(v.y, sc, acc.y) + bb.y;
  acc.z = fmaf(v.z, sc, acc.z) + bb.z;
  acc.w = fmaf(v.w, sc, acc.w) + bb.w;
  ushort4 h4, l4;
  splitbf(acc.x, h4.x, l4.x); splitbf(acc.y, h4.y, l4.y);
  splitbf(acc.z, h4.z, l4.z); splitbf(acc.w, h4.w, l4.w);
  int kc = swzk(wid, lane * 4);
  *(ushort4*)(Ahi + (size_t)wid * HID + kc) = h4;
  *(ushort4*)(Alo + (size_t)wid * HID + kc) = l4;
}

// ---------------- GraphNorm (+ReLU; last layer pools into swizzled bf16 hi/lo) ----------------
__global__ __launch_bounds__(256) void k_gnorm(ushort* __restrict__ Ahi, ushort* __restrict__ Alo,
                                               const int* __restrict__ gstart,
                                               const float* __restrict__ alpha, const float* __restrict__ gamma,
                                               const float* __restrict__ beta,
                                               ushort* __restrict__ Phi, ushort* __restrict__ Plo,
                                               int last) {
  __shared__ float4 smA[4][64];
  __shared__ float4 smB[4][64];
  int g = blockIdx.x;
  int r = threadIdx.x >> 6;        // 0..3
  int cg = threadIdx.x & 63;       // channel group
  int c0 = cg * 4;
  int s = gstart[g], e = gstart[g + 1];
  int n = e - s;
  float cnt = (float)(n > 1 ? n : 1);
  float s1[4] = {0.f, 0.f, 0.f, 0.f}, s2[4] = {0.f, 0.f, 0.f, 0.f};
  for (int i = s + r; i < e; i += 4) {
    int kc = swzk(i, c0);
    ushort4 h = *(const ushort4*)(Ahi + (size_t)i * HID + kc);
    ushort4 l = *(const ushort4*)(Alo + (size_t)i * HID + kc);
    float v0 = joinbf(h.x, l.x), v1 = joinbf(h.y, l.y), v2 = joinbf(h.z, l.z), v3 = joinbf(h.w, l.w);
    s1[0] += v0; s2[0] = fmaf(v0, v0, s2[0]);
    s1[1] += v1; s2[1] = fmaf(v1, v1, s2[1]);
    s1[2] += v2; s2[2] = fmaf(v2, v2, s2[2]);
    s1[3] += v3; s2[3] = fmaf(v3, v3, s2[3]);
  }
  smA[r][cg] = make_float4(s1[0], s1[1], s1[2], s1[3]);
  smB[r][cg] = make_float4(s2[0], s2[1], s2[2], s2[3]);
  __syncthreads();
  float4 a0 = smA[0][cg], a1 = smA[1][cg], a2 = smA[2][cg], a3 = smA[3][cg];
  float4 b0 = smB[0][cg], b1 = smB[1][cg], b2 = smB[2][cg], b3 = smB[3][cg];
  float t1[4] = {a0.x + a1.x + a2.x + a3.x, a0.y + a1.y + a2.y + a3.y,
                 a0.z + a1.z + a2.z + a3.z, a0.w + a1.w + a2.w + a3.w};
  float t2[4] = {b0.x + b1.x + b2.x + b3.x, b0.y + b1.y + b2.y + b3.y,
                 b0.z + b1.z + b2.z + b3.z, b0.w + b1.w + b2.w + b3.w};
  float4 al4 = *(const float4*)(alpha + c0);
  float4 ga4 = *(const float4*)(gamma + c0);
  float4 be4 = *(const float4*)(beta + c0);
  float am[4], rs[4];
  float alv[4] = {al4.x, al4.y, al4.z, al4.w};
  float gav[4] = {ga4.x, ga4.y, ga4.z, ga4.w};
  float bev[4] = {be4.x, be4.y, be4.z, be4.w};
#pragma unroll
  for (int j = 0; j < 4; ++j) {
    float mean = t1[j] / cnt;
    float a = alv[j] * mean;
    float var = t2[j] / cnt - 2.f * a * mean + a * a;
    am[j] = a;
    rs[j] = rsqrtf(var + EPSV) * gav[j];
  }
  if (last) {
    float p[4] = {0.f, 0.f, 0.f, 0.f};
    for (int i = s + r; i < e; i += 4) {
      int kc = swzk(i, c0);
      ushort4 h = *(const ushort4*)(Ahi + (size_t)i * HID + kc);
      ushort4 l = *(const ushort4*)(Alo + (size_t)i * HID + kc);
      float v[4] = {joinbf(h.x, l.x), joinbf(h.y, l.y), joinbf(h.z, l.z), joinbf(h.w, l.w)};
#pragma unroll
      for (int j = 0; j < 4; ++j) p[j] += fmaxf((v[j] - am[j]) * rs[j] + bev[j], 0.f);
    }
    __syncthreads();   // WAR on smA
    smA[r][cg] = make_float4(p[0], p[1], p[2], p[3]);
    __syncthreads();
    if (r == 0) {
      float4 p0 = smA[0][cg], p1 = smA[1][cg], p2 = smA[2][cg], p3 = smA[3][cg];
      float tp[4] = {p0.x + p1.x + p2.x + p3.x, p0.y + p1.y + p2.y + p3.y,
                     p0.z + p1.z + p2.z + p3.z, p0.w + p1.w + p2.w + p3.w};
      ushort4 h4, l4;
      splitbf(tp[0], h4.x, l4.x); splitbf(tp[1], h4.y, l4.y);
      splitbf(tp[2], h4.z, l4.z); splitbf(tp[3], h4.w, l4.w);
      int kc = swzk(g, c0);
      *(ushort4*)(Phi + (size_t)g * HID + kc) = h4;
      *(ushort4*)(Plo + (size_t)g * HID + kc) = l4;
    }
  } else {
    for (int i = s + r; i < e; i += 4) {
      int kc = swzk(i, c0);
      ushort4 h = *(const ushort4*)(Ahi + (size_t)i * HID + kc);
      ushort4 l = *(const ushort4*)(Alo + (size_t)i * HID + kc);
      float v[4] = {joinbf(h.x, l.x), joinbf(h.y, l.y), joinbf(h.z, l.z), joinbf(h.w, l.w)};
      ushort4 ho, lo4;
      float o0 = fmaxf((v[0] - am[0]) * rs[0] + bev[0], 0.f);
      float o1 = fmaxf((v[1] - am[1]) * rs[1] + bev[1], 0.f);
      float o2 = fmaxf((v[2] - am[2]) * rs[2] + bev[2], 0.f);
      float o3 = fmaxf((v[3] - am[3]) * rs[3] + bev[3], 0.f);
      splitbf(o0, ho.x, lo4.x); splitbf(o1, ho.y, lo4.y);
      splitbf(o2, ho.z, lo4.z); splitbf(o3, ho.w, lo4.w);
      *(ushort4*)(Ahi + (size_t)i * HID + kc) = ho;
      *(ushort4*)(Alo + (size_t)i * HID + kc) = lo4;
    }
  }
}

// ---------------- head epilogue: relu(H2+b1) . Wout -> sigmoid ----------------
__global__ __launch_bounds__(256) void k_head2(const float* __restrict__ H2, const float* __restrict__ b1,
                                               const float* __restrict__ Wout, const float* __restrict__ bout,
                                               float* __restrict__ out) {
  int g0 = blockIdx.x * 4, t = threadIdx.x;
  __shared__ float red[4][HID];
  float b = b1[t];
  float wo = Wout[t];
#pragma unroll
  for (int gg = 0; gg < 4; ++gg) {
    float v = H2[(size_t)(g0 + gg) * HID + t] + b;
    red[gg][t] = fmaxf(v, 0.f) * wo;
  }
  __syncthreads();
  for (int off = 128; off > 0; off >>= 1) {
    if (t < off) {
#pragma unroll
      for (int gg = 0; gg < 4; ++gg) red[gg][t] += red[gg][t + off];
    }
    __syncthreads();
  }
  if (t < 4) out[g0 + t] = 1.f / (1.f + __expf(-(red[t][0] + bout[0])));
}

// ---------------- launch ----------------
extern "C" void kernel_launch(void* const* d_in, const int* in_sizes, int n_in,
                              void* d_out, int out_size, void* d_ws, size_t ws_size,
                              hipStream_t stream) {
  const float* x          = (const float*)d_in[0];
  const int*   edge_index = (const int*)d_in[1];
  const int*   batch      = (const int*)d_in[2];
  const float* lin0_W     = (const float*)d_in[3];
  const float* lin0_b     = (const float*)d_in[4];
  const float* conv_W     = (const float*)d_in[5];
  const float* conv_b     = (const float*)d_in[6];
  const float* n_alpha    = (const float*)d_in[7];
  const float* n_gamma    = (const float*)d_in[8];
  const float* n_beta     = (const float*)d_in[9];
  const float* lin1_W     = (const float*)d_in[10];
  const float* lin1_b     = (const float*)d_in[11];
  const float* out_W      = (const float*)d_in[12];
  const float* out_b      = (const float*)d_in[13];
  float* out = (float*)d_out;

  char* ws = (char*)d_ws;
  size_t off = 0;
  auto nxt = [&](size_t bytes) { size_t o = off; off += (bytes + 255) & ~(size_t)255; return o; };
  ushort* Ahi    = (ushort*)(ws + nxt((size_t)NN * HID * 2));
  ushort* Alo    = (ushort*)(ws + nxt((size_t)NN * HID * 2));
  float*  Tbuf   = (float*) (ws + nxt((size_t)NN * HID * 4));   // also head GEMM output
  float*  dinv   = (float*) (ws + nxt((size_t)NN * 4));
  int*    deg    = (int*)   (ws + nxt((size_t)NN * 4));
  int*    rstart = (int*)   (ws + nxt((size_t)(NN + 1) * 4));
  int*    csrsrc = (int*)   (ws + nxt((size_t)NE * 4));
  int*    gstart = (int*)   (ws + nxt((size_t)(NG + 1) * 4));
  char*   poolbase = ws + nxt((size_t)NG * HID * 4);       // 2,048,000 B block, sub-carved:
  int*    pos    = (int*)(poolbase);                        //   [0, 400000) dead after csr_fill
  ushort* Whi    = (ushort*)(poolbase + 400384);            //   dead after last layer gemm
  ushort* Wlo    = (ushort*)(poolbase + 793600);
  ushort* W1hi   = (ushort*)(ws + nxt((size_t)HID * HID * 2));
  ushort* W1lo   = (ushort*)(ws + nxt((size_t)HID * HID * 2));
  ushort* W0hi   = (ushort*)(ws + nxt((size_t)HID * KPAD * 2));
  ushort* W0lo   = (ushort*)(ws + nxt((size_t)HID * KPAD * 2));
  ushort* Phi    = (ushort*)(ws + nxt((size_t)2048 * HID * 2));  // pooled hi (2048-row padded)
  ushort* Plo    = (ushort*)(ws + nxt((size_t)2048 * HID * 2));  // pooled lo
  int*    part   = (int*)   (ws + nxt((size_t)NCHUNK * 4));
  (void)ws_size; (void)in_sizes; (void)n_in; (void)out_size;

  hipMemsetAsync(deg, 0, (size_t)NN * 4, stream);
  k_deg<<<(NE + 255) / 256, 256, 0, stream>>>(edge_index, deg);
  k_scanA<<<NCHUNK, 256, 0, stream>>>(deg, part);
  k_scanB<<<1, 128, 0, stream>>>(part);
  k_scanC<<<NCHUNK, 256, 0, stream>>>(deg, part, rstart, pos, dinv);
  k_csr_fill<<<(NE + 255) / 256, 256, 0, stream>>>(edge_index, pos, csrsrc);
  k_misc<<<MB_GS + MB_WC + MB_W0C + MB_W1C, 256, 0, stream>>>(batch, gstart, conv_W, Whi, Wlo,
                                                              lin0_W, W0hi, W0lo, lin1_W, W1hi, W1lo);

  // fused lin0 + conv0 -> Tbuf  (x staged in-kernel; A never hits global)
  k_l0conv<<<(NN + 63) / 64, 512, 0, stream>>>(x, W0hi, W0lo, lin0_b, Whi, Wlo, Tbuf);

  for (int l = 0; l < 3; ++l) {
    if (l > 0)
      k_gemm_mfma<<<(NN + GBM - 1) / GBM, 512, 0, stream>>>(
          Ahi, Alo, Whi + (size_t)l * HID * HID, Wlo + (size_t)l * HID * HID, Tbuf, NN);
    k_aggregate<<<(NN + 3) / 4, 256, 0, stream>>>(Tbuf, dinv, rstart, csrsrc, conv_b + l * HID, Ahi, Alo);
    k_gnorm<<<NG, 256, 0, stream>>>(Ahi, Alo, gstart, n_alpha + l * HID, n_gamma + l * HID, n_beta + l * HID,
                                    Phi, Plo, l == 2 ? 1 : 0);
  }
  // head: pooled(bf16 hi/lo) @ W1^T via MFMA, then bias+relu+dot+sigmoid
  k_gemm_mfma<<<(NG + GBM - 1) / GBM, 512, 0, stream>>>(Phi, Plo, W1hi, W1lo, Tbuf, NG);
  k_head2<<<NG / 4, 256, 0, stream>>>(Tbuf, lin1_b, out_W, out_b, out);
}

// Round 18
// 624.559 us; speedup vs baseline: 1.0644x; 1.0073x over previous
//
#include <hip/hip_runtime.h>
#include <math.h>

#define NN 100000   // nodes
#define NE 300000   // edges
#define NG 2000     // graphs
#define HID 256
#define CIN 59
#define KPAD 64     // CIN padded to MFMA K
#define EPSV 1e-5f

#define SCAN_CHUNK 1024
#define NCHUNK ((NN + SCAN_CHUNK - 1) / SCAN_CHUNK)   // 98

typedef __attribute__((ext_vector_type(8))) short bf16x8;   // 8 bf16 (4 VGPRs)
typedef __attribute__((ext_vector_type(4))) float f32x4;

// Activations (and pooled) live in a row-swizzled global layout: element
// (r,k) at ushort index r*HID + (k ^ ((r&7)<<3)).  Linear global->LDS copy
// then yields conflict-free ds_read_b128 in the GEMM.
__device__ __forceinline__ int swzk(int row, int k) { return k ^ ((row & 7) << 3); }

// ---------- f32 -> (bf16 hi, bf16 lo) split, round-to-nearest ----------
__device__ inline void splitbf(float x, ushort& hi, ushort& lo) {
  union { float f; unsigned u; } a; a.f = x;
  unsigned r = a.u + 0x7FFFu + ((a.u >> 16) & 1u);
  hi = (ushort)(r >> 16);
  union { unsigned u; float f; } h; h.u = (unsigned)hi << 16;
  union { float f; unsigned u; } d; d.f = x - h.f;
  unsigned r2 = d.u + 0x7FFFu + ((d.u >> 16) & 1u);
  lo = (ushort)(r2 >> 16);
}
__device__ inline float joinbf(ushort hi, ushort lo) {
  union { unsigned u; float f; } a, b;
  a.u = (unsigned)hi << 16; b.u = (unsigned)lo << 16;
  return a.f + b.f;
}

__device__ __forceinline__ void gload16(const ushort* g, ushort* l) {
  __builtin_amdgcn_global_load_lds(
      (const __attribute__((address_space(1))) unsigned int*)g,
      (__attribute__((address_space(3))) unsigned int*)l, 16, 0, 0);
}

// ---------------- degree / CSR build ----------------

__global__ __launch_bounds__(256) void k_deg(const int* __restrict__ ei, int* __restrict__ deg) {
  int e = blockIdx.x * 256 + threadIdx.x;
  if (e < NE) atomicAdd(&deg[ei[NE + e]], 1);   // dst = ei[1][e]
}

__global__ __launch_bounds__(256) void k_scanA(const int* __restrict__ deg, int* __restrict__ part) {
  __shared__ int sm[256];
  int b = blockIdx.x, t = threadIdx.x;
  int base = b * SCAN_CHUNK + t * 4;
  int s = 0;
#pragma unroll
  for (int j = 0; j < 4; ++j) { int idx = base + j; if (idx < NN) s += deg[idx]; }
  sm[t] = s; __syncthreads();
  for (int off = 128; off > 0; off >>= 1) {
    if (t < off) sm[t] += sm[t + off];
    __syncthreads();
  }
  if (t == 0) part[b] = sm[0];
}

__global__ void k_scanB(int* __restrict__ part) {  // 128 threads
  __shared__ int sm[128];
  int t = threadIdx.x;
  int v = (t < NCHUNK) ? part[t] : 0;
  sm[t] = v; __syncthreads();
  for (int off = 1; off < 128; off <<= 1) {
    int x = (t >= off) ? sm[t - off] : 0;
    __syncthreads();
    sm[t] += x;
    __syncthreads();
  }
  if (t < NCHUNK) part[t] = sm[t] - v;  // exclusive
}

// scanC + dinv fused
__global__ __launch_bounds__(256) void k_scanC(const int* __restrict__ deg, const int* __restrict__ part,
                                               int* __restrict__ row_start, int* __restrict__ pos,
                                               float* __restrict__ dinv) {
  __shared__ int sm[256];
  int b = blockIdx.x, t = threadIdx.x;
  int base = b * SCAN_CHUNK + t * 4;
  int v[4]; int s = 0;
#pragma unroll
  for (int j = 0; j < 4; ++j) { int idx = base + j; v[j] = (idx < NN) ? deg[idx] : 0; s += v[j]; }
  sm[t] = s; __syncthreads();
  for (int off = 1; off < 256; off <<= 1) {
    int x = (t >= off) ? sm[t - off] : 0;
    __syncthreads();
    sm[t] += x;
    __syncthreads();
  }
  int excl = sm[t] - s + part[b];
#pragma unroll
  for (int j = 0; j < 4; ++j) {
    int idx = base + j;
    if (idx < NN) {
      row_start[idx] = excl; pos[idx] = excl; excl += v[j];
      dinv[idx] = rsqrtf((float)v[j] + 1.0f);   // +1 self loop
    }
  }
  if (b == 0 && t == 0) row_start[NN] = NE;
}

__global__ __launch_bounds__(256) void k_csr_fill(const int* __restrict__ ei, int* __restrict__ pos,
                                                  int* __restrict__ csr_src) {
  int e = blockIdx.x * 256 + threadIdx.x;
  if (e >= NE) return;
  int d = ei[NE + e];
  int slot = atomicAdd(&pos[d], 1);
  csr_src[slot] = ei[e];
}

// ---------------- merged prep: gstart | conv_W cvt | lin0_W cvt | lin1_W cvt ----------------
#define MB_GS   391
#define MB_WC   768
#define MB_W0C  64
#define MB_W1C  256
__global__ __launch_bounds__(256) void k_misc(const int* __restrict__ batch, int* __restrict__ gstart,
                                              const float* __restrict__ convW, ushort* __restrict__ Whi,
                                              ushort* __restrict__ Wlo,
                                              const float* __restrict__ lin0W, ushort* __restrict__ W0hi,
                                              ushort* __restrict__ W0lo,
                                              const float* __restrict__ W1, ushort* __restrict__ W1hi,
                                              ushort* __restrict__ W1lo) {
  int b = blockIdx.x, t = threadIdx.x;
  if (b < MB_GS) {
    int i = b * 256 + t;
    if (i >= NN) return;
    int bb = batch[i];
    int pb = (i == 0) ? -1 : batch[i - 1];
    for (int g = pb + 1; g <= bb; ++g) gstart[g] = i;
    if (i == NN - 1) {
      for (int g = bb + 1; g <= NG; ++g) gstart[g] = NN;
    }
  } else if (b < MB_GS + MB_WC) {
    int i = (b - MB_GS) * 256 + t;               // < 3*HID*HID
    ushort h, l; splitbf(convW[i], h, l);
    Whi[i] = h; Wlo[i] = l;
  } else if (b < MB_GS + MB_WC + MB_W0C) {
    int i = (b - MB_GS - MB_WC) * 256 + t;       // over 256*64
    int row = i >> 6, k = i & 63;
    float v = (k < CIN) ? lin0W[row * CIN + k] : 0.f;
    ushort h, l; splitbf(v, h, l);
    W0hi[i] = h; W0lo[i] = l;
  } else {
    int i = (b - MB_GS - MB_WC - MB_W0C) * 256 + t;   // over 256*256
    ushort h, l; splitbf(W1[i], h, l);
    W1hi[i] = h; W1lo[i] = l;
  }
}

// ---------------- FUSED lin0 + conv0: T = (elu(x@W0^T+b0)) @ Wc^T ----------------
__global__ __launch_bounds__(512) void k_l0conv(const float* __restrict__ x,
                                                const ushort* __restrict__ W0hi, const ushort* __restrict__ W0lo,
                                                const float* __restrict__ bias0,
                                                const ushort* __restrict__ Wchi, const ushort* __restrict__ Wclo,
                                                float* __restrict__ T) {
  __shared__ ushort sAhi[64 * HID];   // 32 KB
  __shared__ ushort sAlo[64 * HID];   // 32 KB
  __shared__ ushort sXhi[64 * KPAD];  // 8 KB
  __shared__ ushort sXlo[64 * KPAD];  // 8 KB
  int tid = threadIdx.x;
  int wave = tid >> 6, lane = tid & 63;
  int m0 = blockIdx.x * 64;
  int n0 = wave * 32;                 // 32-col slice per wave
  int lr = lane & 15;
  int q  = lane >> 4;
  int kg = q * 8;

  // ---- phase 0: stage x tile (f32 -> bf16 hi/lo, swizzled) ----
  {
    int row = tid >> 3;               // 0..63
    int c0 = (tid & 7) * 8;           // 0..56
    int grow = m0 + row;
    int key = (row & 7) << 3;
    int idx = row * KPAD + (c0 ^ key);
#pragma unroll
    for (int j = 0; j < 8; ++j) {
      int c = c0 + j;
      float v = (grow < NN && c < CIN) ? x[(size_t)grow * CIN + c] : 0.f;
      ushort h, l; splitbf(v, h, l);
      sXhi[idx + j] = h;
      sXlo[idx + j] = l;
    }
  }
  __syncthreads();

  f32x4 acc[4][2];
#pragma unroll
  for (int i = 0; i < 4; ++i)
#pragma unroll
    for (int j = 0; j < 2; ++j) { acc[i][j].x = 0.f; acc[i][j].y = 0.f; acc[i][j].z = 0.f; acc[i][j].w = 0.f; }

  // ---- phase 1: A = elu(X @ W0^T + b0), X from LDS ----
#pragma unroll
  for (int k0 = 0; k0 < KPAD; k0 += 32) {
    bf16x8 ah[4], al[4], bh[2], bl[2];
#pragma unroll
    for (int i = 0; i < 4; ++i) {
      int row = i * 16 + lr;
      int kk = (k0 + kg) ^ ((row & 7) << 3);
      ah[i] = *(const bf16x8*)&sXhi[row * KPAD + kk];
      al[i] = *(const bf16x8*)&sXlo[row * KPAD + kk];
    }
#pragma unroll
    for (int j = 0; j < 2; ++j) {
      int col = n0 + j * 16 + lr;
      bh[j] = *(const bf16x8*)(W0hi + (size_t)col * KPAD + k0 + kg);
      bl[j] = *(const bf16x8*)(W0lo + (size_t)col * KPAD + k0 + kg);
    }
#pragma unroll
    for (int i = 0; i < 4; ++i)
#pragma unroll
      for (int j = 0; j < 2; ++j) {
        acc[i][j] = __builtin_amdgcn_mfma_f32_16x16x32_bf16(ah[i], bh[j], acc[i][j], 0, 0, 0);
        acc[i][j] = __builtin_amdgcn_mfma_f32_16x16x32_bf16(ah[i], bl[j], acc[i][j], 0, 0, 0);
        acc[i][j] = __builtin_amdgcn_mfma_f32_16x16x32_bf16(al[i], bh[j], acc[i][j], 0, 0, 0);
      }
  }
  // ---- epilogue: bias + ELU + split -> separate hi/lo LDS (swzk key) ----
  float bb[2];
#pragma unroll
  for (int j = 0; j < 2; ++j) bb[j] = bias0[n0 + j * 16 + lr];
  // C/D: col = lane&15, row = (lane>>4)*4 + reg
#pragma unroll
  for (int i = 0; i < 4; ++i) {
#pragma unroll
    for (int r = 0; r < 4; ++r) {
      int row = i * 16 + q * 4 + r;             // local row 0..63
      int key = (row & 7) << 3;                 // ushort-index XOR key
#pragma unroll
      for (int j = 0; j < 2; ++j) {
        int col = n0 + j * 16 + lr;
        float v = acc[i][j][r] + bb[j];
        v = v > 0.f ? v : __expf(v) - 1.f;      // ELU (fast path)
        ushort h, l; splitbf(v, h, l);
        int idx = row * HID + (col ^ key);
        sAhi[idx] = h;
        sAlo[idx] = l;
      }
    }
  }
  __syncthreads();

  // ---- phase 2: T = A @ Wc^T, A from LDS (direct bf16x8), W dbuf from L2 ----
#pragma unroll
  for (int i = 0; i < 4; ++i)
#pragma unroll
    for (int j = 0; j < 2; ++j) { acc[i][j].x = 0.f; acc[i][j].y = 0.f; acc[i][j].z = 0.f; acc[i][j].w = 0.f; }

  const ushort* pWh[2]; const ushort* pWl[2];
#pragma unroll
  for (int j = 0; j < 2; ++j) {
    int col = n0 + j * 16 + lr;
    pWh[j] = Wchi + (size_t)col * HID + kg;
    pWl[j] = Wclo + (size_t)col * HID + kg;
  }
  bf16x8 bhc[2], blc[2];
#pragma unroll
  for (int j = 0; j < 2; ++j) { bhc[j] = *(const bf16x8*)pWh[j]; blc[j] = *(const bf16x8*)pWl[j]; }

#pragma unroll 1
  for (int k0 = 0; k0 < HID; k0 += 32) {
    int k1 = (k0 + 32 < HID) ? k0 + 32 : 0;
    bf16x8 bhn[2], bln[2];
#pragma unroll
    for (int j = 0; j < 2; ++j) {       // issue next-step W loads first
      bhn[j] = *(const bf16x8*)(pWh[j] + k1);
      bln[j] = *(const bf16x8*)(pWl[j] + k1);
    }
    bf16x8 ah[4], al[4];
#pragma unroll
    for (int i = 0; i < 4; ++i) {       // A from LDS, unpack-free
      int row = i * 16 + lr;
      int kk = swzk(row, k0 + kg);
      ah[i] = *(const bf16x8*)&sAhi[row * HID + kk];
      al[i] = *(const bf16x8*)&sAlo[row * HID + kk];
    }
#pragma unroll
    for (int i = 0; i < 4; ++i)
#pragma unroll
      for (int j = 0; j < 2; ++j) {
        acc[i][j] = __builtin_amdgcn_mfma_f32_16x16x32_bf16(ah[i], bhc[j], acc[i][j], 0, 0, 0);
        acc[i][j] = __builtin_amdgcn_mfma_f32_16x16x32_bf16(ah[i], blc[j], acc[i][j], 0, 0, 0);
        acc[i][j] = __builtin_amdgcn_mfma_f32_16x16x32_bf16(al[i], bhc[j], acc[i][j], 0, 0, 0);
      }
#pragma unroll
    for (int j = 0; j < 2; ++j) { bhc[j] = bhn[j]; blc[j] = bln[j]; }
  }
  // write T  (C/D: col = lane&15, row = (lane>>4)*4 + reg)
#pragma unroll
  for (int i = 0; i < 4; ++i) {
#pragma unroll
    for (int r = 0; r < 4; ++r) {
      int row = m0 + i * 16 + q * 4 + r;
      if (row < NN) {
        float* cp = T + (size_t)row * HID + n0 + lr;
        cp[0]  = acc[i][0][r];
        cp[16] = acc[i][1][r];
      }
    }
  }
}

// ---------------- MFMA split-bf16 GEMM: C = A @ W^T ----------------
// 64-row tile, 8 waves (512 thr), wave = 64x32 slice; full-K A hi+lo in LDS.
#define GBM 64
__global__ __launch_bounds__(512) void k_gemm_mfma(const ushort* __restrict__ Ahi, const ushort* __restrict__ Alo,
                                                   const ushort* __restrict__ Whi, const ushort* __restrict__ Wlo,
                                                   float* __restrict__ C, int M) {
  __shared__ ushort sAhi[GBM * HID];   // 32 KB, linear copy of swizzled global
  __shared__ ushort sAlo[GBM * HID];   // 32 KB
  int tid = threadIdx.x;
  int wave = tid >> 6, lane = tid & 63;
  int m0 = blockIdx.x * GBM;
  int n0 = wave * 32;
  int lr = lane & 15;
  int q  = lane >> 4;
  int kg = q * 8;

  // ---- stage A tile: 32 segments x 1024 B per buffer, 4 per wave ----
  const ushort* gh = Ahi + (size_t)m0 * HID;
  const ushort* gl = Alo + (size_t)m0 * HID;
#pragma unroll
  for (int sgm = 0; sgm < 4; ++sgm) {
    int seg = sgm * 8 + wave;            // 0..31
    gload16(gh + seg * 512 + lane * 8, &sAhi[seg * 512]);
    gload16(gl + seg * 512 + lane * 8, &sAlo[seg * 512]);
  }

  const ushort* pWh[2]; const ushort* pWl[2];
#pragma unroll
  for (int j = 0; j < 2; ++j) {
    int col = n0 + j * 16 + lr;
    pWh[j] = Whi + (size_t)col * HID + kg;
    pWl[j] = Wlo + (size_t)col * HID + kg;
  }
  bf16x8 bhc[2], blc[2];
#pragma unroll
  for (int j = 0; j < 2; ++j) { bhc[j] = *(const bf16x8*)pWh[j]; blc[j] = *(const bf16x8*)pWl[j]; }

  __syncthreads();   // A tile ready

  f32x4 acc[4][2];
#pragma unroll
  for (int i = 0; i < 4; ++i)
#pragma unroll
    for (int j = 0; j < 2; ++j) { acc[i][j].x = 0.f; acc[i][j].y = 0.f; acc[i][j].z = 0.f; acc[i][j].w = 0.f; }

#pragma unroll 1
  for (int k0 = 0; k0 < HID; k0 += 32) {
    int k1 = (k0 + 32 < HID) ? k0 + 32 : 0;
    bf16x8 bhn[2], bln[2];
#pragma unroll
    for (int j = 0; j < 2; ++j) {       // issue next-step W loads first
      bhn[j] = *(const bf16x8*)(pWh[j] + k1);
      bln[j] = *(const bf16x8*)(pWl[j] + k1);
    }
    bf16x8 ah[4], al[4];
#pragma unroll
    for (int i = 0; i < 4; ++i) {
      int row = i * 16 + lr;
      int kk = swzk(row, k0 + kg);
      ah[i] = *(const bf16x8*)&sAhi[row * HID + kk];
      al[i] = *(const bf16x8*)&sAlo[row * HID + kk];
    }
#pragma unroll
    for (int i = 0; i < 4; ++i)
#pragma unroll
      for (int j = 0; j < 2; ++j) {
        acc[i][j] = __builtin_amdgcn_mfma_f32_16x16x32_bf16(ah[i], bhc[j], acc[i][j], 0, 0, 0);
        acc[i][j] = __builtin_amdgcn_mfma_f32_16x16x32_bf16(ah[i], blc[j], acc[i][j], 0, 0, 0);
        acc[i][j] = __builtin_amdgcn_mfma_f32_16x16x32_bf16(al[i], bhc[j], acc[i][j], 0, 0, 0);
      }
#pragma unroll
    for (int j = 0; j < 2; ++j) { bhc[j] = bhn[j]; blc[j] = bln[j]; }
  }
#pragma unroll
  for (int i = 0; i < 4; ++i) {
#pragma unroll
    for (int r = 0; r < 4; ++r) {
      int row = m0 + i * 16 + q * 4 + r;
      if (row < M) {
        float* cp = C + (size_t)row * HID + n0 + lr;
        cp[0]  = acc[i][0][r];
        cp[16] = acc[i][1][r];
      }
    }
  }
}

// ---------------- aggregate: one wave per dst node, 4-wide edge pipeline ----------------
// XCD-aware block swizzle (T1): 25000 blocks = 8 * 3125 exactly -> bijective.
__global__ __launch_bounds__(256) void k_aggregate(const float* __restrict__ T, const float* __restrict__ dinv,
                                                   const int* __restrict__ row_start, const int* __restrict__ csr_src,
                                                   const float* __restrict__ bias,
                                                   ushort* __restrict__ Ahi, ushort* __restrict__ Alo) {
  int bid = blockIdx.x;
  int sbid = (bid & 7) * 3125 + (bid >> 3);   // XCD chunking
  int wid = sbid * 4 + (threadIdx.x >> 6);
  int lane = threadIdx.x & 63;
  if (wid >= NN) return;
  float di = dinv[wid];
  int s = row_start[wid], e = row_start[wid + 1];
  float4 acc = make_float4(0.f, 0.f, 0.f, 0.f);
  for (int t0 = s; t0 < e; t0 += 4) {
    int sj[4]; float cj[4];
#pragma unroll
    for (int j = 0; j < 4; ++j) {            // 4 index loads in flight
      int t = t0 + j;
      sj[j] = (t < e) ? csr_src[t] : wid;
    }
#pragma unroll
    for (int j = 0; j < 4; ++j) {            // 4 coef loads in flight
      int t = t0 + j;
      cj[j] = (t < e) ? dinv[sj[j]] * di : 0.f;
    }
    float4 r0 = ((const float4*)(T + (size_t)sj[0] * HID))[lane];
    float4 r1 = ((const float4*)(T + (size_t)sj[1] * HID))[lane];
    float4 r2 = ((const float4*)(T + (size_t)sj[2] * HID))[lane];
    float4 r3 = ((const float4*)(T + (size_t)sj[3] * HID))[lane];
    acc.x = fmaf(r0.x, cj[0], acc.x); acc.y = fmaf(r0.y, cj[0], acc.y);
    acc.z = fmaf(r0.z, cj[0], acc.z); acc.w = fmaf(r0.w, cj[0], acc.w);
    acc.x = fmaf(r1.x, cj[1], acc.x); acc.y = fmaf(r1.y, cj[1], acc.y);
    acc.z = fmaf(r1.z, cj[1], acc.z); acc.w = fmaf(r1.w, cj[1], acc.w);
    acc.x = fmaf(r2.x, cj[2], acc.x); acc.y = fmaf(r2.y, cj[2], acc.y);
    acc.z = fmaf(r2.z, cj[2], acc.z); acc.w = fmaf(r2.w, cj[2], acc.w);
    acc.x = fmaf(r3.x, cj[3], acc.x); acc.y = fmaf(r3.y, cj[3], acc.y);
    acc.z = fmaf(r3.z, cj[3], acc.z); acc.w = fmaf(r3.w, cj[3], acc.w);
  }
  float4 v = ((const float4*)(T + (size_t)wid * HID))[lane];
  float sc = di * di;
  float4 bb = ((const float4*)bias)[lane];
  acc.x = fmaf(v.x, sc, acc.x) + bb.x;
  acc.y = fmaf(v.y, sc, acc.y) + bb.y;
  acc.z = fmaf(v.z, sc, acc.z) + bb.z;
  acc.w = fmaf(v.w, sc, acc.w) + bb.w;
  ushort4 h4, l4;
  splitbf(acc.x, h4.x, l4.x); splitbf(acc.y, h4.y, l4.y);
  splitbf(acc.z, h4.z, l4.z); splitbf(acc.w, h4.w, l4.w);
  int kc = swzk(wid, lane * 4);
  *(ushort4*)(Ahi + (size_t)wid * HID + kc) = h4;
  *(ushort4*)(Alo + (size_t)wid * HID + kc) = l4;
}

// ---------------- GraphNorm (+ReLU; last layer pools into swizzled bf16 hi/lo) ----------------
__global__ __launch_bounds__(256) void k_gnorm(ushort* __restrict__ Ahi, ushort* __restrict__ Alo,
                                               const int* __restrict__ gstart,
                                               const float* __restrict__ alpha, const float* __restrict__ gamma,
                                               const float* __restrict__ beta,
                                               ushort* __restrict__ Phi, ushort* __restrict__ Plo,
                                               int last) {
  __shared__ float4 smA[4][64];
  __shared__ float4 smB[4][64];
  int g = blockIdx.x;
  int r = threadIdx.x >> 6;        // 0..3
  int cg = threadIdx.x & 63;       // channel group
  int c0 = cg * 4;
  int s = gstart[g], e = gstart[g + 1];
  int n = e - s;
  float cnt = (float)(n > 1 ? n : 1);
  float s1[4] = {0.f, 0.f, 0.f, 0.f}, s2[4] = {0.f, 0.f, 0.f, 0.f};
  for (int i = s + r; i < e; i += 4) {
    int kc = swzk(i, c0);
    ushort4 h = *(const ushort4*)(Ahi + (size_t)i * HID + kc);
    ushort4 l = *(const ushort4*)(Alo + (size_t)i * HID + kc);
    float v0 = joinbf(h.x, l.x), v1 = joinbf(h.y, l.y), v2 = joinbf(h.z, l.z), v3 = joinbf(h.w, l.w);
    s1[0] += v0; s2[0] = fmaf(v0, v0, s2[0]);
    s1[1] += v1; s2[1] = fmaf(v1, v1, s2[1]);
    s1[2] += v2; s2[2] = fmaf(v2, v2, s2[2]);
    s1[3] += v3; s2[3] = fmaf(v3, v3, s2[3]);
  }
  smA[r][cg] = make_float4(s1[0], s1[1], s1[2], s1[3]);
  smB[r][cg] = make_float4(s2[0], s2[1], s2[2], s2[3]);
  __syncthreads();
  float4 a0 = smA[0][cg], a1 = smA[1][cg], a2 = smA[2][cg], a3 = smA[3][cg];
  float4 b0 = smB[0][cg], b1 = smB[1][cg], b2 = smB[2][cg], b3 = smB[3][cg];
  float t1[4] = {a0.x + a1.x + a2.x + a3.x, a0.y + a1.y + a2.y + a3.y,
                 a0.z + a1.z + a2.z + a3.z, a0.w + a1.w + a2.w + a3.w};
  float t2[4] = {b0.x + b1.x + b2.x + b3.x, b0.y + b1.y + b2.y + b3.y,
                 b0.z + b1.z + b2.z + b3.z, b0.w + b1.w + b2.w + b3.w};
  float4 al4 = *(const float4*)(alpha + c0);
  float4 ga4 = *(const float4*)(gamma + c0);
  float4 be4 = *(const float4*)(beta + c0);
  float am[4], rs[4];
  float alv[4] = {al4.x, al4.y, al4.z, al4.w};
  float gav[4] = {ga4.x, ga4.y, ga4.z, ga4.w};
  float bev[4] = {be4.x, be4.y, be4.z, be4.w};
#pragma unroll
  for (int j = 0; j < 4; ++j) {
    float mean = t1[j] / cnt;
    float a = alv[j] * mean;
    float var = t2[j] / cnt - 2.f * a * mean + a * a;
    am[j] = a;
    rs[j] = rsqrtf(var + EPSV) * gav[j];
  }
  if (last) {
    float p[4] = {0.f, 0.f, 0.f, 0.f};
    for (int i = s + r; i < e; i += 4) {
      int kc = swzk(i, c0);
      ushort4 h = *(const ushort4*)(Ahi + (size_t)i * HID + kc);
      ushort4 l = *(const ushort4*)(Alo + (size_t)i * HID + kc);
      float v[4] = {joinbf(h.x, l.x), joinbf(h.y, l.y), joinbf(h.z, l.z), joinbf(h.w, l.w)};
#pragma unroll
      for (int j = 0; j < 4; ++j) p[j] += fmaxf((v[j] - am[j]) * rs[j] + bev[j], 0.f);
    }
    __syncthreads();   // WAR on smA
    smA[r][cg] = make_float4(p[0], p[1], p[2], p[3]);
    __syncthreads();
    if (r == 0) {
      float4 p0 = smA[0][cg], p1 = smA[1][cg], p2 = smA[2][cg], p3 = smA[3][cg];
      float tp[4] = {p0.x + p1.x + p2.x + p3.x, p0.y + p1.y + p2.y + p3.y,
                     p0.z + p1.z + p2.z + p3.z, p0.w + p1.w + p2.w + p3.w};
      ushort4 h4, l4;
      splitbf(tp[0], h4.x, l4.x); splitbf(tp[1], h4.y, l4.y);
      splitbf(tp[2], h4.z, l4.z); splitbf(tp[3], h4.w, l4.w);
      int kc = swzk(g, c0);
      *(ushort4*)(Phi + (size_t)g * HID + kc) = h4;
      *(ushort4*)(Plo + (size_t)g * HID + kc) = l4;
    }
  } else {
    for (int i = s + r; i < e; i += 4) {
      int kc = swzk(i, c0);
      ushort4 h = *(const ushort4*)(Ahi + (size_t)i * HID + kc);
      ushort4 l = *(const ushort4*)(Alo + (size_t)i * HID + kc);
      float v[4] = {joinbf(h.x, l.x), joinbf(h.y, l.y), joinbf(h.z, l.z), joinbf(h.w, l.w)};
      ushort4 ho, lo4;
      float o0 = fmaxf((v[0] - am[0]) * rs[0] + bev[0], 0.f);
      float o1 = fmaxf((v[1] - am[1]) * rs[1] + bev[1], 0.f);
      float o2 = fmaxf((v[2] - am[2]) * rs[2] + bev[2], 0.f);
      float o3 = fmaxf((v[3] - am[3]) * rs[3] + bev[3], 0.f);
      splitbf(o0, ho.x, lo4.x); splitbf(o1, ho.y, lo4.y);
      splitbf(o2, ho.z, lo4.z); splitbf(o3, ho.w, lo4.w);
      *(ushort4*)(Ahi + (size_t)i * HID + kc) = ho;
      *(ushort4*)(Alo + (size_t)i * HID + kc) = lo4;
    }
  }
}

// ---------------- head epilogue: relu(H2+b1) . Wout -> sigmoid ----------------
__global__ __launch_bounds__(256) void k_head2(const float* __restrict__ H2, const float* __restrict__ b1,
                                               const float* __restrict__ Wout, const float* __restrict__ bout,
                                               float* __restrict__ out) {
  int g0 = blockIdx.x * 4, t = threadIdx.x;
  __shared__ float red[4][HID];
  float b = b1[t];
  float wo = Wout[t];
#pragma unroll
  for (int gg = 0; gg < 4; ++gg) {
    float v = H2[(size_t)(g0 + gg) * HID + t] + b;
    red[gg][t] = fmaxf(v, 0.f) * wo;
  }
  __syncthreads();
  for (int off = 128; off > 0; off >>= 1) {
    if (t < off) {
#pragma unroll
      for (int gg = 0; gg < 4; ++gg) red[gg][t] += red[gg][t + off];
    }
    __syncthreads();
  }
  if (t < 4) out[g0 + t] = 1.f / (1.f + __expf(-(red[t][0] + bout[0])));
}

// ---------------- launch ----------------
extern "C" void kernel_launch(void* const* d_in, const int* in_sizes, int n_in,
                              void* d_out, int out_size, void* d_ws, size_t ws_size,
                              hipStream_t stream) {
  const float* x          = (const float*)d_in[0];
  const int*   edge_index = (const int*)d_in[1];
  const int*   batch      = (const int*)d_in[2];
  const float* lin0_W     = (const float*)d_in[3];
  const float* lin0_b     = (const float*)d_in[4];
  const float* conv_W     = (const float*)d_in[5];
  const float* conv_b     = (const float*)d_in[6];
  const float* n_alpha    = (const float*)d_in[7];
  const float* n_gamma    = (const float*)d_in[8];
  const float* n_beta     = (const float*)d_in[9];
  const float* lin1_W     = (const float*)d_in[10];
  const float* lin1_b     = (const float*)d_in[11];
  const float* out_W      = (const float*)d_in[12];
  const float* out_b      = (const float*)d_in[13];
  float* out = (float*)d_out;

  char* ws = (char*)d_ws;
  size_t off = 0;
  auto nxt = [&](size_t bytes) { size_t o = off; off += (bytes + 255) & ~(size_t)255; return o; };
  ushort* Ahi    = (ushort*)(ws + nxt((size_t)NN * HID * 2));
  ushort* Alo    = (ushort*)(ws + nxt((size_t)NN * HID * 2));
  float*  Tbuf   = (float*) (ws + nxt((size_t)NN * HID * 4));   // also head GEMM output
  float*  dinv   = (float*) (ws + nxt((size_t)NN * 4));
  int*    deg    = (int*)   (ws + nxt((size_t)NN * 4));
  int*    rstart = (int*)   (ws + nxt((size_t)(NN + 1) * 4));
  int*    csrsrc = (int*)   (ws + nxt((size_t)NE * 4));
  int*    gstart = (int*)   (ws + nxt((size_t)(NG + 1) * 4));
  char*   poolbase = ws + nxt((size_t)NG * HID * 4);       // 2,048,000 B block, sub-carved:
  int*    pos    = (int*)(poolbase);                        //   [0, 400000) dead after csr_fill
  ushort* Whi    = (ushort*)(poolbase + 400384);            //   dead after last layer gemm
  ushort* Wlo    = (ushort*)(poolbase + 793600);
  ushort* W1hi   = (ushort*)(ws + nxt((size_t)HID * HID * 2));
  ushort* W1lo   = (ushort*)(ws + nxt((size_t)HID * HID * 2));
  ushort* W0hi   = (ushort*)(ws + nxt((size_t)HID * KPAD * 2));
  ushort* W0lo   = (ushort*)(ws + nxt((size_t)HID * KPAD * 2));
  ushort* Phi    = (ushort*)(ws + nxt((size_t)2048 * HID * 2));  // pooled hi (2048-row padded)
  ushort* Plo    = (ushort*)(ws + nxt((size_t)2048 * HID * 2));  // pooled lo
  int*    part   = (int*)   (ws + nxt((size_t)NCHUNK * 4));
  (void)ws_size; (void)in_sizes; (void)n_in; (void)out_size;

  hipMemsetAsync(deg, 0, (size_t)NN * 4, stream);
  k_deg<<<(NE + 255) / 256, 256, 0, stream>>>(edge_index, deg);
  k_scanA<<<NCHUNK, 256, 0, stream>>>(deg, part);
  k_scanB<<<1, 128, 0, stream>>>(part);
  k_scanC<<<NCHUNK, 256, 0, stream>>>(deg, part, rstart, pos, dinv);
  k_csr_fill<<<(NE + 255) / 256, 256, 0, stream>>>(edge_index, pos, csrsrc);
  k_misc<<<MB_GS + MB_WC + MB_W0C + MB_W1C, 256, 0, stream>>>(batch, gstart, conv_W, Whi, Wlo,
                                                              lin0_W, W0hi, W0lo, lin1_W, W1hi, W1lo);

  // fused lin0 + conv0 -> Tbuf  (x staged in-kernel; A never hits global)
  k_l0conv<<<(NN + 63) / 64, 512, 0, stream>>>(x, W0hi, W0lo, lin0_b, Whi, Wlo, Tbuf);

  for (int l = 0; l < 3; ++l) {
    if (l > 0)
      k_gemm_mfma<<<(NN + GBM - 1) / GBM, 512, 0, stream>>>(
          Ahi, Alo, Whi + (size_t)l * HID * HID, Wlo + (size_t)l * HID * HID, Tbuf, NN);
    k_aggregate<<<(NN + 3) / 4, 256, 0, stream>>>(Tbuf, dinv, rstart, csrsrc, conv_b + l * HID, Ahi, Alo);
    k_gnorm<<<NG, 256, 0, stream>>>(Ahi, Alo, gstart, n_alpha + l * HID, n_gamma + l * HID, n_beta + l * HID,
                                    Phi, Plo, l == 2 ? 1 : 0);
  }
  // head: pooled(bf16 hi/lo) @ W1^T via MFMA, then bias+relu+dot+sigmoid
  k_gemm_mfma<<<(NG + GBM - 1) / GBM, 512, 0, stream>>>(Phi, Plo, W1hi, W1lo, Tbuf, NG);
  k_head2<<<NG / 4, 256, 0, stream>>>(Tbuf, lin1_b, out_W, out_b, out);
}